// Round 10
// baseline (515.529 us; speedup 1.0000x reference)
//
#include <hip/hip_runtime.h>
#include <hip/hip_bf16.h>
#include <math.h>

typedef __bf16 bf16_t;
typedef __bf16 bf16x8 __attribute__((ext_vector_type(8)));
typedef float f32x4v __attribute__((ext_vector_type(4)));
typedef unsigned short ushort_t;

#define SL_TOTAL 8064
#define SL_PAD 8192
#define DMODEL 2048
#define NHEAD 16
#define HDIM 128
#define SEQ 252

__device__ __forceinline__ bf16_t f2bf(float f) {
  unsigned u = __builtin_bit_cast(unsigned, f);
  u += 0x7fffu + ((u >> 16) & 1u);
  ushort_t h = (ushort_t)(u >> 16);
  return __builtin_bit_cast(bf16_t, h);
}
__device__ __forceinline__ float bf2f(bf16_t b) {
  unsigned u = ((unsigned)__builtin_bit_cast(ushort_t, b)) << 16;
  return __builtin_bit_cast(float, u);
}

// ---------------- fused 4-weight f32 -> bf16 convert ----------------
__global__ __launch_bounds__(256) void cvt4_kernel(const float* __restrict__ s0,
                                                   const float* __restrict__ s1,
                                                   const float* __restrict__ s2,
                                                   const float* __restrict__ s3,
                                                   bf16_t* __restrict__ d0,
                                                   bf16_t* __restrict__ d1,
                                                   bf16_t* __restrict__ d2,
                                                   bf16_t* __restrict__ d3) {
  const float* src; bf16_t* dst;
  switch (blockIdx.y) {
    case 0: src = s0; dst = d0; break;
    case 1: src = s1; dst = d1; break;
    case 2: src = s2; dst = d2; break;
    default: src = s3; dst = d3; break;
  }
  int i = (blockIdx.x * 256 + threadIdx.x) * 8;
  float4 a = *(const float4*)(src + i);
  float4 b = *(const float4*)(src + i + 4);
  bf16x8 o;
  o[0] = f2bf(a.x); o[1] = f2bf(a.y); o[2] = f2bf(a.z); o[3] = f2bf(a.w);
  o[4] = f2bf(b.x); o[5] = f2bf(b.y); o[6] = f2bf(b.z); o[7] = f2bf(b.w);
  *(bf16x8*)(dst + i) = o;
}

__global__ __launch_bounds__(256) void cvt_kernel(const float* __restrict__ src,
                                                  bf16_t* __restrict__ dst, int n) {
  int i = (blockIdx.x * 256 + threadIdx.x) * 8;
  if (i >= n) return;
  float4 a = *(const float4*)(src + i);
  float4 b = *(const float4*)(src + i + 4);
  bf16x8 o;
  o[0] = f2bf(a.x); o[1] = f2bf(a.y); o[2] = f2bf(a.z); o[3] = f2bf(a.w);
  o[4] = f2bf(b.x); o[5] = f2bf(b.y); o[6] = f2bf(b.z); o[7] = f2bf(b.w);
  *(bf16x8*)(dst + i) = o;
}

// ---------------- fused dual LayerNorm (f32 in, bf16 out) ----------------
__global__ __launch_bounds__(256) void ln_kernel(
    const float* __restrict__ sem, const float* __restrict__ vgg,
    const float* __restrict__ w1, const float* __restrict__ b1,
    const float* __restrict__ w2, const float* __restrict__ b2,
    bf16_t* __restrict__ o1, bf16_t* __restrict__ o2) {
  const float* x; const float* w; const float* bb; bf16_t* o;
  int row = blockIdx.x;
  if (blockIdx.y == 0) { x = sem; w = w1; bb = b1; o = o1; }
  else                 { x = vgg; w = w2; bb = b2; o = o2; }
  x += (size_t)row * DMODEL; o += (size_t)row * DMODEL;
  int t = threadIdx.x, wid = t >> 6, lane = t & 63;
  float4 va = *(const float4*)(x + t * 8);
  float4 vb = *(const float4*)(x + t * 8 + 4);
  float s  = va.x + va.y + va.z + va.w + vb.x + vb.y + vb.z + vb.w;
  float ss = va.x*va.x + va.y*va.y + va.z*va.z + va.w*va.w
           + vb.x*vb.x + vb.y*vb.y + vb.z*vb.z + vb.w*vb.w;
  #pragma unroll
  for (int m = 1; m < 64; m <<= 1) { s += __shfl_xor(s, m); ss += __shfl_xor(ss, m); }
  __shared__ float rs[4], rss[4];
  if (lane == 0) { rs[wid] = s; rss[wid] = ss; }
  __syncthreads();
  float st = rs[0] + rs[1] + rs[2] + rs[3];
  float sst = rss[0] + rss[1] + rss[2] + rss[3];
  float mu = st * (1.0f / 2048.0f);
  float var = sst * (1.0f / 2048.0f) - mu * mu;
  float rstd = rsqrtf(var + 1e-6f);
  float4 wa = *(const float4*)(w + t * 8);
  float4 wb = *(const float4*)(w + t * 8 + 4);
  float4 ba = *(const float4*)(bb + t * 8);
  float4 bb4 = *(const float4*)(bb + t * 8 + 4);
  bf16x8 ov;
  ov[0] = f2bf((va.x - mu) * rstd * wa.x + ba.x);
  ov[1] = f2bf((va.y - mu) * rstd * wa.y + ba.y);
  ov[2] = f2bf((va.z - mu) * rstd * wa.z + ba.z);
  ov[3] = f2bf((va.w - mu) * rstd * wa.w + ba.w);
  ov[4] = f2bf((vb.x - mu) * rstd * wb.x + bb4.x);
  ov[5] = f2bf((vb.y - mu) * rstd * wb.y + bb4.y);
  ov[6] = f2bf((vb.z - mu) * rstd * wb.z + bb4.z);
  ov[7] = f2bf((vb.w - mu) * rstd * wb.w + bb4.w);
  *(bf16x8*)(o + t * 8) = ov;
}

// ======== 128x128 BT-GEMM, BK=32, 4 blocks/CU (TLP-overlap design) ========
// 256 threads = 4 waves (2M x 2N), per-wave 64x64 out (acc[4][4] = 64 VGPR).
// LDS = 2 buf x (128A+128B) x 32 x 2B = 32 KiB -> 4 blocks/CU = 4 waves/SIMD.
// Cross-block wave skew (no inter-block barriers) lets one block's MFMA hide
// another's LDS reads / staging drain (m114 mechanism) -- the lever all
// lockstep 256^2 schedules (r4-r8, MfmaUtil 37%) were missing.
// BK=32 rows are 64B: 2-bit XOR swizzle (g ^= row&3) -> 4 lanes/bank on
// ds_read_b128 (1.58x, m136) -- acceptable, LDS issue ~25% of MFMA demand.
// EPI 0: bf16.  1: relu(v+bias[col]) bf16.  2: v*tanh(gate) f32.  3: dual bf16.
template <int EPI>
__global__ __launch_bounds__(256, 4) void gemm128(
    const bf16_t* __restrict__ A, const bf16_t* __restrict__ B,
    void* __restrict__ C, void* __restrict__ C2,
    const float* __restrict__ bias, const float* __restrict__ gatep,
    int Mreal, int N, int K, int nnt) {
  __shared__ bf16_t As[2][128 * 32];
  __shared__ bf16_t Bs[2][128 * 32];
  const int nblk = gridDim.x;
  const int orig = blockIdx.x;
  const int qd = nblk >> 3, rr = nblk & 7, xc = orig & 7, lin = orig >> 3;
  const int wg = (xc < rr ? xc * (qd + 1) : rr * (qd + 1) + (xc - rr) * qd) + lin;
  const int mtile = wg / nnt, ntile = wg - mtile * nnt;
  const int m0 = mtile * 128, n0 = ntile * 128;

  const int tid = threadIdx.x;
  const int wid = tid >> 6, lane = tid & 63;
  const int l15 = lane & 15, l4 = lane >> 4;
  const int wm = (wid >> 1) * 64, wn = (wid & 1) * 64;
  const int srow = lane >> 2;                      // row within 16-row chunk
  const int scol = 8 * ((lane & 3) ^ (srow & 3));  // pre-swizzled src col (elems)

  f32x4v acc[4][4] = {};
  const int nkt = K >> 5;

  auto stage = [&](int kt, int buf) {
    const int k0 = kt << 5;
    #pragma unroll
    for (int q = 0; q < 2; ++q) {
      int chunk = wid * 2 + q;                     // 0..7
      int row = chunk * 16 + srow;
      const bf16_t* ga = A + (size_t)(m0 + row) * K + k0 + scol;
      const bf16_t* gb = B + (size_t)(n0 + row) * K + k0 + scol;
      __builtin_amdgcn_global_load_lds((const __attribute__((address_space(1))) unsigned int*)ga,
          (__attribute__((address_space(3))) unsigned int*)(&As[buf][chunk * 512]), 16, 0, 0);
      __builtin_amdgcn_global_load_lds((const __attribute__((address_space(1))) unsigned int*)gb,
          (__attribute__((address_space(3))) unsigned int*)(&Bs[buf][chunk * 512]), 16, 0, 0);
    }
  };

  stage(0, 0);
  for (int kt = 0; kt < nkt; ++kt) {
    int buf = kt & 1;
    __syncthreads();
    if (kt + 1 < nkt) stage(kt + 1, buf ^ 1);
    const char* as = (const char*)As[buf];
    const char* bs = (const char*)Bs[buf];
    bf16x8 af[4], bfv[4];
    #pragma unroll
    for (int mi = 0; mi < 4; ++mi) {
      int row = wm + mi * 16 + l15;
      af[mi] = *(const bf16x8*)(as + row * 64 + ((l4 ^ (row & 3)) << 4));
    }
    #pragma unroll
    for (int ni = 0; ni < 4; ++ni) {
      int row = wn + ni * 16 + l15;
      bfv[ni] = *(const bf16x8*)(bs + row * 64 + ((l4 ^ (row & 3)) << 4));
    }
    #pragma unroll
    for (int mi = 0; mi < 4; ++mi)
      #pragma unroll
      for (int ni = 0; ni < 4; ++ni)
        acc[mi][ni] = __builtin_amdgcn_mfma_f32_16x16x32_bf16(af[mi], bfv[ni], acc[mi][ni], 0, 0, 0);
    __syncthreads();
  }

  float scale = 1.0f;
  if (EPI == 2) scale = tanhf(gatep[0]);
  bf16_t* Cb = (bf16_t*)C;
  int colbase = n0;
  int ldc = N;
  if (EPI == 3) {
    ldc = 2048;
    if (n0 >= 2048) { Cb = (bf16_t*)C2; colbase = n0 - 2048; }
  }
  #pragma unroll
  for (int mi = 0; mi < 4; ++mi) {
    #pragma unroll
    for (int ni = 0; ni < 4; ++ni) {
      int c = colbase + wn + ni * 16 + l15;
      #pragma unroll
      for (int j = 0; j < 4; ++j) {
        int r = m0 + wm + mi * 16 + 4 * l4 + j;
        if (r >= Mreal) continue;
        float v = acc[mi][ni][j];
        if (EPI == 1) { v += bias[c]; v = v > 0.0f ? v : 0.0f; }
        if (EPI == 2) ((float*)C)[(size_t)r * N + c] = v * scale;
        else Cb[(size_t)r * ldc + c] = f2bf(v);
      }
    }
  }
}

// ---------------- gate_score = sigmoid(semLN @ gate_w^T + gate_b) ----------
__global__ __launch_bounds__(256) void gate_kernel(const bf16_t* __restrict__ a,
                                                   const float* __restrict__ gw,
                                                   const float* __restrict__ gb,
                                                   float* __restrict__ gs) {
  int r0 = blockIdx.x * 4;
  int t = threadIdx.x;
  int j = t >> 5, lt = t & 31;
  const float* wr = gw + (size_t)j * DMODEL;
  float sum[4] = {0.0f, 0.0f, 0.0f, 0.0f};
  #pragma unroll
  for (int u = 0; u < 8; ++u) {
    int i = lt * 8 + u * 256;
    float4 w0 = *(const float4*)(wr + i);
    float4 w1 = *(const float4*)(wr + i + 4);
    #pragma unroll
    for (int r = 0; r < 4; ++r) {
      bf16x8 av = *(const bf16x8*)(a + (size_t)(r0 + r) * DMODEL + i);
      sum[r] += bf2f(av[0]) * w0.x + bf2f(av[1]) * w0.y + bf2f(av[2]) * w0.z + bf2f(av[3]) * w0.w
              + bf2f(av[4]) * w1.x + bf2f(av[5]) * w1.y + bf2f(av[6]) * w1.z + bf2f(av[7]) * w1.w;
    }
  }
  #pragma unroll
  for (int m = 1; m < 32; m <<= 1) {
    #pragma unroll
    for (int r = 0; r < 4; ++r) sum[r] += __shfl_xor(sum[r], m);
  }
  if (lt == 0) {
    #pragma unroll
    for (int r = 0; r < 4; ++r)
      gs[(size_t)(r0 + r) * 8 + j] = 1.0f / (1.0f + __expf(-(sum[r] + gb[j])));
  }
}

// ------------- key bias = log(sigmoid(hidden @ w2^T + b2) + 0.1) ----------
__global__ __launch_bounds__(256) void imp_kernel(const bf16_t* __restrict__ hid,
                                                  const float* __restrict__ w2,
                                                  const float* __restrict__ b2,
                                                  float* __restrict__ kb) {
  int row = blockIdx.x * 4 + (threadIdx.x >> 6);
  int lane = threadIdx.x & 63;
  const bf16_t* hr = hid + (size_t)row * 512;
  bf16x8 hv = *(const bf16x8*)(hr + lane * 8);
  float sum = 0.0f;
  #pragma unroll
  for (int i = 0; i < 8; ++i) sum += bf2f(hv[i]) * w2[lane * 8 + i];
  #pragma unroll
  for (int m = 1; m < 64; m <<= 1) sum += __shfl_xor(sum, m);
  if (lane == 0) {
    float imp = 1.0f / (1.0f + __expf(-(sum + b2[0])));
    kb[row] = logf(imp + 0.1f);
  }
}

// ---------------- attention (round-8 best-known) --------------------------
__global__ __launch_bounds__(512, 1) void attn_kernel(
    const bf16_t* __restrict__ Q, const bf16_t* __restrict__ K,
    const bf16_t* __restrict__ V, const float* __restrict__ gs,
    const float* __restrict__ kb, bf16_t* __restrict__ O) {
  __shared__ bf16_t Kt[64 * 128];       // [key][d] swizzled
  __shared__ bf16_t Vt[128 * 64];       // [d][key] swizzled
  __shared__ bf16_t Pl[8][32 * 72];     // per-wave P scratch
  __shared__ float kyf[256], kxf[256], kbl[256];

  const int bi = blockIdx.x >> 4;
  const int h = blockIdx.x & 15;
  const int tid = threadIdx.x;
  const int wid = tid >> 6;
  const int lane = tid & 63;
  const int l15 = lane & 15, l4 = lane >> 4;
  const bool hs = (h < 8);

  for (int i = tid; i < 256; i += 512) {
    kyf[i] = (float)(i / 18);
    kxf[i] = (float)(i % 18);
    int kk = i < SEQ ? i : SEQ - 1;
    kbl[i] = kb[bi * SEQ + kk];
  }

  const int q0 = wid * 32;
  bf16x8 qf[2][4];
  #pragma unroll
  for (int mi = 0; mi < 2; ++mi) {
    int q = q0 + mi * 16 + l15; if (q >= SEQ) q = SEQ - 1;
    const bf16_t* qp = Q + (size_t)(bi * SEQ + q) * DMODEL + h * HDIM;
    #pragma unroll
    for (int ki = 0; ki < 4; ++ki) qf[mi][ki] = *(const bf16x8*)(qp + ki * 32 + l4 * 8);
  }

  const float invdiag = 1.0f / (sqrtf(520.0f) + 1e-6f);
  float gsd[2][4], qyv[2][4], qxv[2][4];
  #pragma unroll
  for (int mi = 0; mi < 2; ++mi)
    #pragma unroll
    for (int j = 0; j < 4; ++j) {
      int q = q0 + mi * 16 + 4 * l4 + j;
      int qc = q < SEQ ? q : SEQ - 1;
      gsd[mi][j] = hs ? gs[(size_t)(bi * SEQ + qc) * 8 + h] * invdiag : 0.0f;
      qyv[mi][j] = (float)(q / 18);
      qxv[mi][j] = (float)(q % 18);
    }

  f32x4v oacc[2][8] = {};
  f32x4v osum[2] = {};
  const float scl = 0.08838834764831845f;       // 1/sqrt(128)
  bf16_t* Plw = &Pl[wid][0];
  bf16x8 vones;
  #pragma unroll
  for (int i = 0; i < 8; ++i) vones[i] = f2bf(1.0f);

  for (int t = 0; t < 4; ++t) {
    __syncthreads();
    #pragma unroll
    for (int rep = 0; rep < 2; ++rep) {
      int s = tid + rep * 512;
      int row = s >> 4, cb = s & 15;
      int kk = t * 64 + row;
      uint4 val = make_uint4(0, 0, 0, 0);
      if (kk < SEQ) val = *(const uint4*)(K + (size_t)(bi * SEQ + kk) * DMODEL + h * HDIM + cb * 8);
      *(uint4*)((char*)Kt + row * 256 + ((cb * 16) ^ ((row & 7) << 4))) = val;
    }
    {
      int kp = tid >> 4, db = tid & 15;
      int k0i = t * 64 + kp * 2, k1i = k0i + 1;
      uint4 a = make_uint4(0, 0, 0, 0), c4 = make_uint4(0, 0, 0, 0);
      if (k0i < SEQ) a = *(const uint4*)(V + (size_t)(bi * SEQ + k0i) * DMODEL + h * HDIM + db * 8);
      if (k1i < SEQ) c4 = *(const uint4*)(V + (size_t)(bi * SEQ + k1i) * DMODEL + h * HDIM + db * 8);
      const ushort_t* au = (const ushort_t*)&a;
      const ushort_t* cu = (const ushort_t*)&c4;
      #pragma unroll
      for (int i = 0; i < 8; ++i) {
        int d = db * 8 + i;
        unsigned pv = (unsigned)au[i] | ((unsigned)cu[i] << 16);
        *(unsigned*)((char*)Vt + d * 128 + ((kp * 4) ^ ((d & 7) << 4))) = pv;
      }
    }
    __syncthreads();

    f32x4v sc[2][4] = {};
    #pragma unroll
    for (int ki = 0; ki < 4; ++ki) {
      bf16x8 kf[4];
      #pragma unroll
      for (int ni = 0; ni < 4; ++ni) {
        int row = ni * 16 + l15;
        kf[ni] = *(const bf16x8*)((char*)Kt + row * 256 + ((ki * 64 + l4 * 16) ^ ((row & 7) << 4)));
      }
      #pragma unroll
      for (int mi = 0; mi < 2; ++mi)
        #pragma unroll
        for (int ni = 0; ni < 4; ++ni)
          sc[mi][ni] = __builtin_amdgcn_mfma_f32_16x16x32_bf16(qf[mi][ki], kf[ni], sc[mi][ni], 0, 0, 0);
    }

    #pragma unroll
    for (int mi = 0; mi < 2; ++mi) {
      #pragma unroll
      for (int j = 0; j < 4; ++j) {
        int prow = mi * 16 + 4 * l4 + j;
        #pragma unroll
        for (int ni = 0; ni < 4; ++ni) {
          int kk = t * 64 + ni * 16 + l15;
          float s = sc[mi][ni][j] * scl + kbl[kk];
          if (hs) {
            float dy = qyv[mi][j] - kyf[kk];
            float dx = qxv[mi][j] - kxf[kk];
            s -= sqrtf(dy * dy + dx * dx) * gsd[mi][j];
          }
          float p = (kk < SEQ) ? __expf(s) : 0.0f;
          Plw[prow * 72 + ni * 16 + l15] = f2bf(p);
        }
      }
    }

    #pragma unroll
    for (int ks = 0; ks < 2; ++ks) {
      bf16x8 pf[2];
      #pragma unroll
      for (int mi = 0; mi < 2; ++mi)
        pf[mi] = *(const bf16x8*)(Plw + (mi * 16 + l15) * 72 + ks * 32 + l4 * 8);
      #pragma unroll
      for (int mi = 0; mi < 2; ++mi)
        osum[mi] = __builtin_amdgcn_mfma_f32_16x16x32_bf16(pf[mi], vones, osum[mi], 0, 0, 0);
      #pragma unroll
      for (int di = 0; di < 8; ++di) {
        int d = di * 16 + l15;
        bf16x8 vf = *(const bf16x8*)((char*)Vt + d * 128 + ((ks * 64 + l4 * 16) ^ ((d & 7) << 4)));
        #pragma unroll
        for (int mi = 0; mi < 2; ++mi)
          oacc[mi][di] = __builtin_amdgcn_mfma_f32_16x16x32_bf16(pf[mi], vf, oacc[mi][di], 0, 0, 0);
      }
    }
  }

  #pragma unroll
  for (int mi = 0; mi < 2; ++mi) {
    #pragma unroll
    for (int j = 0; j < 4; ++j) {
      int q = q0 + mi * 16 + 4 * l4 + j;
      if (q >= SEQ) continue;
      float inv = 1.0f / osum[mi][j];
      bf16_t* op = O + (size_t)(bi * SEQ + q) * DMODEL + h * HDIM;
      #pragma unroll
      for (int di = 0; di < 8; ++di)
        op[di * 16 + l15] = f2bf(oacc[mi][di][j] * inv);
    }
  }
}

// --------------------------------------------------------------------------
extern "C" void kernel_launch(void* const* d_in, const int* in_sizes, int n_in,
                              void* d_out, int out_size, void* d_ws, size_t ws_size,
                              hipStream_t stream) {
  const float* sem  = (const float*)d_in[0];
  const float* vgg  = (const float*)d_in[1];
  const float* ln1w = (const float*)d_in[3];
  const float* ln1b = (const float*)d_in[4];
  const float* ln2w = (const float*)d_in[5];
  const float* ln2b = (const float*)d_in[6];
  const float* Wq   = (const float*)d_in[7];
  const float* Wk   = (const float*)d_in[8];
  const float* Wv   = (const float*)d_in[9];
  const float* Wo   = (const float*)d_in[10];
  const float* w1   = (const float*)d_in[11];
  const float* b1   = (const float*)d_in[12];
  const float* w2   = (const float*)d_in[13];
  const float* b2   = (const float*)d_in[14];
  const float* gw   = (const float*)d_in[15];
  const float* gb   = (const float*)d_in[16];
  const float* gate = (const float*)d_in[17];

  char* ws = (char*)d_ws;
  const size_t SZ_W    = 8388608;    // 2048*2048*2
  const size_t SZ_PAD  = 33554432;   // 8192*2048*2 (padded activations, A-side)
  const size_t SZ_ACT  = 33030144;   // 8064*2048*2
  bf16_t* Wqb  = (bf16_t*)(ws + 0);
  bf16_t* Wkb  = (bf16_t*)(ws + SZ_W);       // Wk;Wv contiguous = fused KV weight
  bf16_t* Wvb  = (bf16_t*)(ws + 2 * SZ_W);
  bf16_t* Wob  = (bf16_t*)(ws + 3 * SZ_W);
  bf16_t* w1b  = (bf16_t*)(ws + 4 * SZ_W);                     // 2 MB
  bf16_t* semb = (bf16_t*)(ws + 4 * SZ_W + 2097152);           // padded; attn-out alias
  bf16_t* vggb = (bf16_t*)(ws + 4 * SZ_W + 2097152 + SZ_PAD);  // padded
  bf16_t* Vb   = (bf16_t*)(ws + 4 * SZ_W + 2097152 + 2 * SZ_PAD);
  bf16_t* hidb = (bf16_t*)(ws + 4 * SZ_W + 2097152 + 2 * SZ_PAD + SZ_ACT);
  float*  gsb  = (float*)(ws + 4 * SZ_W + 2097152 + 2 * SZ_PAD + SZ_ACT + 8257536);
  float*  kbb  = (float*)(ws + 4 * SZ_W + 2097152 + 2 * SZ_PAD + SZ_ACT + 8257536 + 258048);
  // Q and K (8064 rows each, bf16) exactly fill d_out (8064*2048*4 B)
  bf16_t* Qb = (bf16_t*)d_out;
  bf16_t* Kb = (bf16_t*)((char*)d_out + SZ_ACT);
  bf16_t* attnb = semb;

  cvt4_kernel<<<dim3(2048, 4), 256, 0, stream>>>(Wq, Wk, Wv, Wo, Wqb, Wkb, Wvb, Wob);
  cvt_kernel<<<512, 256, 0, stream>>>(w1, w1b, 1048576);
  ln_kernel<<<dim3(8064, 2), 256, 0, stream>>>(sem, vgg, ln1w, ln1b, ln2w, ln2b, semb, vggb);

  // Q projection: 8192(pad)x2048x2048 -> 64x16 tiles
  gemm128<0><<<1024, 256, 0, stream>>>(semb, Wqb, Qb, nullptr, nullptr, nullptr,
                                       8064, 2048, 2048, 16);
  // fused K+V projection: 8192(pad)x4096x2048 -> 64x32 tiles
  gemm128<3><<<2048, 256, 0, stream>>>(vggb, Wkb, Kb, Vb, nullptr, nullptr,
                                       8064, 4096, 2048, 32);
  // importance hidden: 8192(pad)x512x2048, relu+bias -> 64x4 tiles
  gemm128<1><<<256, 256, 0, stream>>>(semb, w1b, hidb, nullptr, b1, nullptr,
                                      8064, 512, 2048, 4);

  gate_kernel<<<2016, 256, 0, stream>>>(semb, gw, gb, gsb);
  imp_kernel<<<2016, 256, 0, stream>>>(hidb, w2, b2, kbb);

  attn_kernel<<<512, 512, 0, stream>>>(Qb, Kb, Vb, gsb, kbb, attnb);

  // output projection: 8192(pad)x2048x2048, *tanh(gate), f32 out
  gemm128<2><<<1024, 256, 0, stream>>>(attnb, Wob, d_out, nullptr, nullptr, gate,
                                       8064, 2048, 2048, 16);
}

// Round 11
// 514.214 us; speedup vs baseline: 1.0026x; 1.0026x over previous
//
#include <hip/hip_runtime.h>
#include <hip/hip_bf16.h>
#include <math.h>

typedef __bf16 bf16_t;
typedef __bf16 bf16x8 __attribute__((ext_vector_type(8)));
typedef float f32x4v __attribute__((ext_vector_type(4)));
typedef unsigned short ushort_t;

#define SL_TOTAL 8064
#define SL_PAD 8192
#define DMODEL 2048
#define NHEAD 16
#define HDIM 128
#define SEQ 252

__device__ __forceinline__ bf16_t f2bf(float f) {
  unsigned u = __builtin_bit_cast(unsigned, f);
  u += 0x7fffu + ((u >> 16) & 1u);
  ushort_t h = (ushort_t)(u >> 16);
  return __builtin_bit_cast(bf16_t, h);
}
__device__ __forceinline__ float bf2f(bf16_t b) {
  unsigned u = ((unsigned)__builtin_bit_cast(ushort_t, b)) << 16;
  return __builtin_bit_cast(float, u);
}

// ---------------- fused 4-weight f32 -> bf16 convert ----------------
__global__ __launch_bounds__(256) void cvt4_kernel(const float* __restrict__ s0,
                                                   const float* __restrict__ s1,
                                                   const float* __restrict__ s2,
                                                   const float* __restrict__ s3,
                                                   bf16_t* __restrict__ d0,
                                                   bf16_t* __restrict__ d1,
                                                   bf16_t* __restrict__ d2,
                                                   bf16_t* __restrict__ d3) {
  const float* src; bf16_t* dst;
  switch (blockIdx.y) {
    case 0: src = s0; dst = d0; break;
    case 1: src = s1; dst = d1; break;
    case 2: src = s2; dst = d2; break;
    default: src = s3; dst = d3; break;
  }
  int i = (blockIdx.x * 256 + threadIdx.x) * 8;
  float4 a = *(const float4*)(src + i);
  float4 b = *(const float4*)(src + i + 4);
  bf16x8 o;
  o[0] = f2bf(a.x); o[1] = f2bf(a.y); o[2] = f2bf(a.z); o[3] = f2bf(a.w);
  o[4] = f2bf(b.x); o[5] = f2bf(b.y); o[6] = f2bf(b.z); o[7] = f2bf(b.w);
  *(bf16x8*)(dst + i) = o;
}

__global__ __launch_bounds__(256) void cvt_kernel(const float* __restrict__ src,
                                                  bf16_t* __restrict__ dst, int n) {
  int i = (blockIdx.x * 256 + threadIdx.x) * 8;
  if (i >= n) return;
  float4 a = *(const float4*)(src + i);
  float4 b = *(const float4*)(src + i + 4);
  bf16x8 o;
  o[0] = f2bf(a.x); o[1] = f2bf(a.y); o[2] = f2bf(a.z); o[3] = f2bf(a.w);
  o[4] = f2bf(b.x); o[5] = f2bf(b.y); o[6] = f2bf(b.z); o[7] = f2bf(b.w);
  *(bf16x8*)(dst + i) = o;
}

// ---------------- fused dual LayerNorm (f32 in, bf16 out) ----------------
__global__ __launch_bounds__(256) void ln_kernel(
    const float* __restrict__ sem, const float* __restrict__ vgg,
    const float* __restrict__ w1, const float* __restrict__ b1,
    const float* __restrict__ w2, const float* __restrict__ b2,
    bf16_t* __restrict__ o1, bf16_t* __restrict__ o2) {
  const float* x; const float* w; const float* bb; bf16_t* o;
  int row = blockIdx.x;
  if (blockIdx.y == 0) { x = sem; w = w1; bb = b1; o = o1; }
  else                 { x = vgg; w = w2; bb = b2; o = o2; }
  x += (size_t)row * DMODEL; o += (size_t)row * DMODEL;
  int t = threadIdx.x, wid = t >> 6, lane = t & 63;
  float4 va = *(const float4*)(x + t * 8);
  float4 vb = *(const float4*)(x + t * 8 + 4);
  float s  = va.x + va.y + va.z + va.w + vb.x + vb.y + vb.z + vb.w;
  float ss = va.x*va.x + va.y*va.y + va.z*va.z + va.w*va.w
           + vb.x*vb.x + vb.y*vb.y + vb.z*vb.z + vb.w*vb.w;
  #pragma unroll
  for (int m = 1; m < 64; m <<= 1) { s += __shfl_xor(s, m); ss += __shfl_xor(ss, m); }
  __shared__ float rs[4], rss[4];
  if (lane == 0) { rs[wid] = s; rss[wid] = ss; }
  __syncthreads();
  float st = rs[0] + rs[1] + rs[2] + rs[3];
  float sst = rss[0] + rss[1] + rss[2] + rss[3];
  float mu = st * (1.0f / 2048.0f);
  float var = sst * (1.0f / 2048.0f) - mu * mu;
  float rstd = rsqrtf(var + 1e-6f);
  float4 wa = *(const float4*)(w + t * 8);
  float4 wb = *(const float4*)(w + t * 8 + 4);
  float4 ba = *(const float4*)(bb + t * 8);
  float4 bb4 = *(const float4*)(bb + t * 8 + 4);
  bf16x8 ov;
  ov[0] = f2bf((va.x - mu) * rstd * wa.x + ba.x);
  ov[1] = f2bf((va.y - mu) * rstd * wa.y + ba.y);
  ov[2] = f2bf((va.z - mu) * rstd * wa.z + ba.z);
  ov[3] = f2bf((va.w - mu) * rstd * wa.w + ba.w);
  ov[4] = f2bf((vb.x - mu) * rstd * wb.x + bb4.x);
  ov[5] = f2bf((vb.y - mu) * rstd * wb.y + bb4.y);
  ov[6] = f2bf((vb.z - mu) * rstd * wb.z + bb4.z);
  ov[7] = f2bf((vb.w - mu) * rstd * wb.w + bb4.w);
  *(bf16x8*)(o + t * 8) = ov;
}

// ======== 128x128 BT-GEMM, BK=32, 4 blocks/CU, FIXED swizzle ========
// 256 threads = 4 waves (2M x 2N), per-wave 64x64 out. LDS 32 KiB -> 4
// blocks/CU = 16 waves/CU: cross-block skew hides barrier drains (m114).
// Conflict-free BK=32 swizzle (round-10 bug fixed): a b128 read's 16 lanes
// (rows r=0..15) land at byte offset ((r&3)*64 + slot*16) mod 256, so the
// slot must vary with (r>>2)&3, NOT r&3. Physical slot = l4 ^ ((row>>2)&3);
// pre-swizzled global source slot = (lane&3) ^ (lane>>4) (same involution,
// rule #21). All 64 lanes then cover 64 distinct 16B cells -> 0 conflicts.
// EPI 0: bf16.  1: relu(v+bias[col]) bf16.  2: v*tanh(gate) f32.  3: dual bf16.
template <int EPI>
__global__ __launch_bounds__(256, 4) void gemm128(
    const bf16_t* __restrict__ A, const bf16_t* __restrict__ B,
    void* __restrict__ C, void* __restrict__ C2,
    const float* __restrict__ bias, const float* __restrict__ gatep,
    int Mreal, int N, int K, int nnt) {
  __shared__ bf16_t As[2][128 * 32];
  __shared__ bf16_t Bs[2][128 * 32];
  const int nblk = gridDim.x;
  const int orig = blockIdx.x;
  const int qd = nblk >> 3, rr = nblk & 7, xc = orig & 7, lin = orig >> 3;
  const int wg = (xc < rr ? xc * (qd + 1) : rr * (qd + 1) + (xc - rr) * qd) + lin;
  const int mtile = wg / nnt, ntile = wg - mtile * nnt;
  const int m0 = mtile * 128, n0 = ntile * 128;

  const int tid = threadIdx.x;
  const int wid = tid >> 6, lane = tid & 63;
  const int l15 = lane & 15, l4 = lane >> 4;
  const int wm = (wid >> 1) * 64, wn = (wid & 1) * 64;
  const int srow = lane >> 2;                       // row within 16-row chunk
  const int scol = 8 * ((lane & 3) ^ (lane >> 4));  // FIXED pre-swizzled src col

  f32x4v acc[4][4] = {};
  const int nkt = K >> 5;

  auto stage = [&](int kt, int buf) {
    const int k0 = kt << 5;
    #pragma unroll
    for (int q = 0; q < 2; ++q) {
      int chunk = wid * 2 + q;                     // 0..7
      int row = chunk * 16 + srow;
      const bf16_t* ga = A + (size_t)(m0 + row) * K + k0 + scol;
      const bf16_t* gb = B + (size_t)(n0 + row) * K + k0 + scol;
      __builtin_amdgcn_global_load_lds((const __attribute__((address_space(1))) unsigned int*)ga,
          (__attribute__((address_space(3))) unsigned int*)(&As[buf][chunk * 512]), 16, 0, 0);
      __builtin_amdgcn_global_load_lds((const __attribute__((address_space(1))) unsigned int*)gb,
          (__attribute__((address_space(3))) unsigned int*)(&Bs[buf][chunk * 512]), 16, 0, 0);
    }
  };

  stage(0, 0);
  for (int kt = 0; kt < nkt; ++kt) {
    int buf = kt & 1;
    __syncthreads();
    if (kt + 1 < nkt) stage(kt + 1, buf ^ 1);
    const char* as = (const char*)As[buf];
    const char* bs = (const char*)Bs[buf];
    bf16x8 af[4], bfv[4];
    #pragma unroll
    for (int mi = 0; mi < 4; ++mi) {
      int row = wm + mi * 16 + l15;
      af[mi] = *(const bf16x8*)(as + row * 64 + ((l4 ^ ((row >> 2) & 3)) << 4));
    }
    #pragma unroll
    for (int ni = 0; ni < 4; ++ni) {
      int row = wn + ni * 16 + l15;
      bfv[ni] = *(const bf16x8*)(bs + row * 64 + ((l4 ^ ((row >> 2) & 3)) << 4));
    }
    #pragma unroll
    for (int mi = 0; mi < 4; ++mi)
      #pragma unroll
      for (int ni = 0; ni < 4; ++ni)
        acc[mi][ni] = __builtin_amdgcn_mfma_f32_16x16x32_bf16(af[mi], bfv[ni], acc[mi][ni], 0, 0, 0);
    __syncthreads();
  }

  float scale = 1.0f;
  if (EPI == 2) scale = tanhf(gatep[0]);
  bf16_t* Cb = (bf16_t*)C;
  int colbase = n0;
  int ldc = N;
  if (EPI == 3) {
    ldc = 2048;
    if (n0 >= 2048) { Cb = (bf16_t*)C2; colbase = n0 - 2048; }
  }
  #pragma unroll
  for (int mi = 0; mi < 4; ++mi) {
    #pragma unroll
    for (int ni = 0; ni < 4; ++ni) {
      int c = colbase + wn + ni * 16 + l15;
      #pragma unroll
      for (int j = 0; j < 4; ++j) {
        int r = m0 + wm + mi * 16 + 4 * l4 + j;
        if (r >= Mreal) continue;
        float v = acc[mi][ni][j];
        if (EPI == 1) { v += bias[c]; v = v > 0.0f ? v : 0.0f; }
        if (EPI == 2) ((float*)C)[(size_t)r * N + c] = v * scale;
        else Cb[(size_t)r * ldc + c] = f2bf(v);
      }
    }
  }
}

// ---------------- gate_score = sigmoid(semLN @ gate_w^T + gate_b) ----------
__global__ __launch_bounds__(256) void gate_kernel(const bf16_t* __restrict__ a,
                                                   const float* __restrict__ gw,
                                                   const float* __restrict__ gb,
                                                   float* __restrict__ gs) {
  int r0 = blockIdx.x * 4;
  int t = threadIdx.x;
  int j = t >> 5, lt = t & 31;
  const float* wr = gw + (size_t)j * DMODEL;
  float sum[4] = {0.0f, 0.0f, 0.0f, 0.0f};
  #pragma unroll
  for (int u = 0; u < 8; ++u) {
    int i = lt * 8 + u * 256;
    float4 w0 = *(const float4*)(wr + i);
    float4 w1 = *(const float4*)(wr + i + 4);
    #pragma unroll
    for (int r = 0; r < 4; ++r) {
      bf16x8 av = *(const bf16x8*)(a + (size_t)(r0 + r) * DMODEL + i);
      sum[r] += bf2f(av[0]) * w0.x + bf2f(av[1]) * w0.y + bf2f(av[2]) * w0.z + bf2f(av[3]) * w0.w
              + bf2f(av[4]) * w1.x + bf2f(av[5]) * w1.y + bf2f(av[6]) * w1.z + bf2f(av[7]) * w1.w;
    }
  }
  #pragma unroll
  for (int m = 1; m < 32; m <<= 1) {
    #pragma unroll
    for (int r = 0; r < 4; ++r) sum[r] += __shfl_xor(sum[r], m);
  }
  if (lt == 0) {
    #pragma unroll
    for (int r = 0; r < 4; ++r)
      gs[(size_t)(r0 + r) * 8 + j] = 1.0f / (1.0f + __expf(-(sum[r] + gb[j])));
  }
}

// ------------- key bias = log(sigmoid(hidden @ w2^T + b2) + 0.1) ----------
__global__ __launch_bounds__(256) void imp_kernel(const bf16_t* __restrict__ hid,
                                                  const float* __restrict__ w2,
                                                  const float* __restrict__ b2,
                                                  float* __restrict__ kb) {
  int row = blockIdx.x * 4 + (threadIdx.x >> 6);
  int lane = threadIdx.x & 63;
  const bf16_t* hr = hid + (size_t)row * 512;
  bf16x8 hv = *(const bf16x8*)(hr + lane * 8);
  float sum = 0.0f;
  #pragma unroll
  for (int i = 0; i < 8; ++i) sum += bf2f(hv[i]) * w2[lane * 8 + i];
  #pragma unroll
  for (int m = 1; m < 64; m <<= 1) sum += __shfl_xor(sum, m);
  if (lane == 0) {
    float imp = 1.0f / (1.0f + __expf(-(sum + b2[0])));
    kb[row] = logf(imp + 0.1f);
  }
}

// ---------------- attention (round-8 best-known) --------------------------
__global__ __launch_bounds__(512, 1) void attn_kernel(
    const bf16_t* __restrict__ Q, const bf16_t* __restrict__ K,
    const bf16_t* __restrict__ V, const float* __restrict__ gs,
    const float* __restrict__ kb, bf16_t* __restrict__ O) {
  __shared__ bf16_t Kt[64 * 128];       // [key][d] swizzled
  __shared__ bf16_t Vt[128 * 64];       // [d][key] swizzled
  __shared__ bf16_t Pl[8][32 * 72];     // per-wave P scratch
  __shared__ float kyf[256], kxf[256], kbl[256];

  const int bi = blockIdx.x >> 4;
  const int h = blockIdx.x & 15;
  const int tid = threadIdx.x;
  const int wid = tid >> 6;
  const int lane = tid & 63;
  const int l15 = lane & 15, l4 = lane >> 4;
  const bool hs = (h < 8);

  for (int i = tid; i < 256; i += 512) {
    kyf[i] = (float)(i / 18);
    kxf[i] = (float)(i % 18);
    int kk = i < SEQ ? i : SEQ - 1;
    kbl[i] = kb[bi * SEQ + kk];
  }

  const int q0 = wid * 32;
  bf16x8 qf[2][4];
  #pragma unroll
  for (int mi = 0; mi < 2; ++mi) {
    int q = q0 + mi * 16 + l15; if (q >= SEQ) q = SEQ - 1;
    const bf16_t* qp = Q + (size_t)(bi * SEQ + q) * DMODEL + h * HDIM;
    #pragma unroll
    for (int ki = 0; ki < 4; ++ki) qf[mi][ki] = *(const bf16x8*)(qp + ki * 32 + l4 * 8);
  }

  const float invdiag = 1.0f / (sqrtf(520.0f) + 1e-6f);
  float gsd[2][4], qyv[2][4], qxv[2][4];
  #pragma unroll
  for (int mi = 0; mi < 2; ++mi)
    #pragma unroll
    for (int j = 0; j < 4; ++j) {
      int q = q0 + mi * 16 + 4 * l4 + j;
      int qc = q < SEQ ? q : SEQ - 1;
      gsd[mi][j] = hs ? gs[(size_t)(bi * SEQ + qc) * 8 + h] * invdiag : 0.0f;
      qyv[mi][j] = (float)(q / 18);
      qxv[mi][j] = (float)(q % 18);
    }

  f32x4v oacc[2][8] = {};
  f32x4v osum[2] = {};
  const float scl = 0.08838834764831845f;       // 1/sqrt(128)
  bf16_t* Plw = &Pl[wid][0];
  bf16x8 vones;
  #pragma unroll
  for (int i = 0; i < 8; ++i) vones[i] = f2bf(1.0f);

  for (int t = 0; t < 4; ++t) {
    __syncthreads();
    #pragma unroll
    for (int rep = 0; rep < 2; ++rep) {
      int s = tid + rep * 512;
      int row = s >> 4, cb = s & 15;
      int kk = t * 64 + row;
      uint4 val = make_uint4(0, 0, 0, 0);
      if (kk < SEQ) val = *(const uint4*)(K + (size_t)(bi * SEQ + kk) * DMODEL + h * HDIM + cb * 8);
      *(uint4*)((char*)Kt + row * 256 + ((cb * 16) ^ ((row & 7) << 4))) = val;
    }
    {
      int kp = tid >> 4, db = tid & 15;
      int k0i = t * 64 + kp * 2, k1i = k0i + 1;
      uint4 a = make_uint4(0, 0, 0, 0), c4 = make_uint4(0, 0, 0, 0);
      if (k0i < SEQ) a = *(const uint4*)(V + (size_t)(bi * SEQ + k0i) * DMODEL + h * HDIM + db * 8);
      if (k1i < SEQ) c4 = *(const uint4*)(V + (size_t)(bi * SEQ + k1i) * DMODEL + h * HDIM + db * 8);
      const ushort_t* au = (const ushort_t*)&a;
      const ushort_t* cu = (const ushort_t*)&c4;
      #pragma unroll
      for (int i = 0; i < 8; ++i) {
        int d = db * 8 + i;
        unsigned pv = (unsigned)au[i] | ((unsigned)cu[i] << 16);
        *(unsigned*)((char*)Vt + d * 128 + ((kp * 4) ^ ((d & 7) << 4))) = pv;
      }
    }
    __syncthreads();

    f32x4v sc[2][4] = {};
    #pragma unroll
    for (int ki = 0; ki < 4; ++ki) {
      bf16x8 kf[4];
      #pragma unroll
      for (int ni = 0; ni < 4; ++ni) {
        int row = ni * 16 + l15;
        kf[ni] = *(const bf16x8*)((char*)Kt + row * 256 + ((ki * 64 + l4 * 16) ^ ((row & 7) << 4)));
      }
      #pragma unroll
      for (int mi = 0; mi < 2; ++mi)
        #pragma unroll
        for (int ni = 0; ni < 4; ++ni)
          sc[mi][ni] = __builtin_amdgcn_mfma_f32_16x16x32_bf16(qf[mi][ki], kf[ni], sc[mi][ni], 0, 0, 0);
    }

    #pragma unroll
    for (int mi = 0; mi < 2; ++mi) {
      #pragma unroll
      for (int j = 0; j < 4; ++j) {
        int prow = mi * 16 + 4 * l4 + j;
        #pragma unroll
        for (int ni = 0; ni < 4; ++ni) {
          int kk = t * 64 + ni * 16 + l15;
          float s = sc[mi][ni][j] * scl + kbl[kk];
          if (hs) {
            float dy = qyv[mi][j] - kyf[kk];
            float dx = qxv[mi][j] - kxf[kk];
            s -= sqrtf(dy * dy + dx * dx) * gsd[mi][j];
          }
          float p = (kk < SEQ) ? __expf(s) : 0.0f;
          Plw[prow * 72 + ni * 16 + l15] = f2bf(p);
        }
      }
    }

    #pragma unroll
    for (int ks = 0; ks < 2; ++ks) {
      bf16x8 pf[2];
      #pragma unroll
      for (int mi = 0; mi < 2; ++mi)
        pf[mi] = *(const bf16x8*)(Plw + (mi * 16 + l15) * 72 + ks * 32 + l4 * 8);
      #pragma unroll
      for (int mi = 0; mi < 2; ++mi)
        osum[mi] = __builtin_amdgcn_mfma_f32_16x16x32_bf16(pf[mi], vones, osum[mi], 0, 0, 0);
      #pragma unroll
      for (int di = 0; di < 8; ++di) {
        int d = di * 16 + l15;
        bf16x8 vf = *(const bf16x8*)((char*)Vt + d * 128 + ((ks * 64 + l4 * 16) ^ ((d & 7) << 4)));
        #pragma unroll
        for (int mi = 0; mi < 2; ++mi)
          oacc[mi][di] = __builtin_amdgcn_mfma_f32_16x16x32_bf16(pf[mi], vf, oacc[mi][di], 0, 0, 0);
      }
    }
  }

  #pragma unroll
  for (int mi = 0; mi < 2; ++mi) {
    #pragma unroll
    for (int j = 0; j < 4; ++j) {
      int q = q0 + mi * 16 + 4 * l4 + j;
      if (q >= SEQ) continue;
      float inv = 1.0f / osum[mi][j];
      bf16_t* op = O + (size_t)(bi * SEQ + q) * DMODEL + h * HDIM;
      #pragma unroll
      for (int di = 0; di < 8; ++di)
        op[di * 16 + l15] = f2bf(oacc[mi][di][j] * inv);
    }
  }
}

// --------------------------------------------------------------------------
extern "C" void kernel_launch(void* const* d_in, const int* in_sizes, int n_in,
                              void* d_out, int out_size, void* d_ws, size_t ws_size,
                              hipStream_t stream) {
  const float* sem  = (const float*)d_in[0];
  const float* vgg  = (const float*)d_in[1];
  const float* ln1w = (const float*)d_in[3];
  const float* ln1b = (const float*)d_in[4];
  const float* ln2w = (const float*)d_in[5];
  const float* ln2b = (const float*)d_in[6];
  const float* Wq   = (const float*)d_in[7];
  const float* Wk   = (const float*)d_in[8];
  const float* Wv   = (const float*)d_in[9];
  const float* Wo   = (const float*)d_in[10];
  const float* w1   = (const float*)d_in[11];
  const float* b1   = (const float*)d_in[12];
  const float* w2   = (const float*)d_in[13];
  const float* b2   = (const float*)d_in[14];
  const float* gw   = (const float*)d_in[15];
  const float* gb   = (const float*)d_in[16];
  const float* gate = (const float*)d_in[17];

  char* ws = (char*)d_ws;
  const size_t SZ_W    = 8388608;    // 2048*2048*2
  const size_t SZ_PAD  = 33554432;   // 8192*2048*2 (padded activations, A-side)
  const size_t SZ_ACT  = 33030144;   // 8064*2048*2
  bf16_t* Wqb  = (bf16_t*)(ws + 0);
  bf16_t* Wkb  = (bf16_t*)(ws + SZ_W);       // Wk;Wv contiguous = fused KV weight
  bf16_t* Wvb  = (bf16_t*)(ws + 2 * SZ_W);
  bf16_t* Wob  = (bf16_t*)(ws + 3 * SZ_W);
  bf16_t* w1b  = (bf16_t*)(ws + 4 * SZ_W);                     // 2 MB
  bf16_t* semb = (bf16_t*)(ws + 4 * SZ_W + 2097152);           // padded; attn-out alias
  bf16_t* vggb = (bf16_t*)(ws + 4 * SZ_W + 2097152 + SZ_PAD);  // padded
  bf16_t* Vb   = (bf16_t*)(ws + 4 * SZ_W + 2097152 + 2 * SZ_PAD);
  bf16_t* hidb = (bf16_t*)(ws + 4 * SZ_W + 2097152 + 2 * SZ_PAD + SZ_ACT);
  float*  gsb  = (float*)(ws + 4 * SZ_W + 2097152 + 2 * SZ_PAD + SZ_ACT + 8257536);
  float*  kbb  = (float*)(ws + 4 * SZ_W + 2097152 + 2 * SZ_PAD + SZ_ACT + 8257536 + 258048);
  // Q and K (8064 rows each, bf16) exactly fill d_out (8064*2048*4 B)
  bf16_t* Qb = (bf16_t*)d_out;
  bf16_t* Kb = (bf16_t*)((char*)d_out + SZ_ACT);
  bf16_t* attnb = semb;

  cvt4_kernel<<<dim3(2048, 4), 256, 0, stream>>>(Wq, Wk, Wv, Wo, Wqb, Wkb, Wvb, Wob);
  cvt_kernel<<<512, 256, 0, stream>>>(w1, w1b, 1048576);
  ln_kernel<<<dim3(8064, 2), 256, 0, stream>>>(sem, vgg, ln1w, ln1b, ln2w, ln2b, semb, vggb);

  // Q projection: 8192(pad)x2048x2048 -> 64x16 tiles, 4 blocks/CU
  gemm128<0><<<1024, 256, 0, stream>>>(semb, Wqb, Qb, nullptr, nullptr, nullptr,
                                       8064, 2048, 2048, 16);
  // fused K+V projection: 8192(pad)x4096x2048 -> 64x32 tiles
  gemm128<3><<<2048, 256, 0, stream>>>(vggb, Wkb, Kb, Vb, nullptr, nullptr,
                                       8064, 4096, 2048, 32);
  // importance hidden: 8192(pad)x512x2048, relu+bias -> 64x4 tiles (all-resident)
  gemm128<1><<<256, 256, 0, stream>>>(semb, w1b, hidb, nullptr, b1, nullptr,
                                      8064, 512, 2048, 4);

  gate_kernel<<<2016, 256, 0, stream>>>(semb, gw, gb, gsb);
  imp_kernel<<<2016, 256, 0, stream>>>(hidb, w2, b2, kbb);

  attn_kernel<<<512, 512, 0, stream>>>(Qb, Kb, Vb, gsb, kbb, attnb);

  // output projection: 8192(pad)x2048x2048, *tanh(gate), f32 out
  gemm128<2><<<1024, 256, 0, stream>>>(attnb, Wob, d_out, nullptr, nullptr, gate,
                                       8064, 2048, 2048, 16);
}

// Round 12
// 474.525 us; speedup vs baseline: 1.0864x; 1.0836x over previous
//
#include <hip/hip_runtime.h>
#include <hip/hip_bf16.h>
#include <math.h>

typedef __bf16 bf16_t;
typedef __bf16 bf16x8 __attribute__((ext_vector_type(8)));
typedef float f32x4v __attribute__((ext_vector_type(4)));
typedef unsigned short ushort_t;

#define SL_TOTAL 8064
#define SL_PAD 8192
#define DMODEL 2048
#define NHEAD 16
#define HDIM 128
#define SEQ 252

__device__ __forceinline__ bf16_t f2bf(float f) {
  unsigned u = __builtin_bit_cast(unsigned, f);
  u += 0x7fffu + ((u >> 16) & 1u);
  ushort_t h = (ushort_t)(u >> 16);
  return __builtin_bit_cast(bf16_t, h);
}
__device__ __forceinline__ float bf2f(bf16_t b) {
  unsigned u = ((unsigned)__builtin_bit_cast(ushort_t, b)) << 16;
  return __builtin_bit_cast(float, u);
}

// ---------------- fused 5-weight f32 -> bf16 convert ----------------
__global__ __launch_bounds__(256) void cvt5_kernel(const float* __restrict__ s0,
                                                   const float* __restrict__ s1,
                                                   const float* __restrict__ s2,
                                                   const float* __restrict__ s3,
                                                   const float* __restrict__ s4,
                                                   bf16_t* __restrict__ d0,
                                                   bf16_t* __restrict__ d1,
                                                   bf16_t* __restrict__ d2,
                                                   bf16_t* __restrict__ d3,
                                                   bf16_t* __restrict__ d4) {
  const float* src; bf16_t* dst; int n = 4194304;
  switch (blockIdx.y) {
    case 0: src = s0; dst = d0; break;
    case 1: src = s1; dst = d1; break;
    case 2: src = s2; dst = d2; break;
    case 3: src = s3; dst = d3; break;
    default: src = s4; dst = d4; n = 1048576; break;
  }
  int i = (blockIdx.x * 256 + threadIdx.x) * 8;
  if (i >= n) return;
  float4 a = *(const float4*)(src + i);
  float4 b = *(const float4*)(src + i + 4);
  bf16x8 o;
  o[0] = f2bf(a.x); o[1] = f2bf(a.y); o[2] = f2bf(a.z); o[3] = f2bf(a.w);
  o[4] = f2bf(b.x); o[5] = f2bf(b.y); o[6] = f2bf(b.z); o[7] = f2bf(b.w);
  *(bf16x8*)(dst + i) = o;
}

// ---------------- fused dual LayerNorm (f32 in, bf16 out) ----------------
__global__ __launch_bounds__(256) void ln_kernel(
    const float* __restrict__ sem, const float* __restrict__ vgg,
    const float* __restrict__ w1, const float* __restrict__ b1,
    const float* __restrict__ w2, const float* __restrict__ b2,
    bf16_t* __restrict__ o1, bf16_t* __restrict__ o2) {
  const float* x; const float* w; const float* bb; bf16_t* o;
  int row = blockIdx.x;
  if (blockIdx.y == 0) { x = sem; w = w1; bb = b1; o = o1; }
  else                 { x = vgg; w = w2; bb = b2; o = o2; }
  x += (size_t)row * DMODEL; o += (size_t)row * DMODEL;
  int t = threadIdx.x, wid = t >> 6, lane = t & 63;
  float4 va = *(const float4*)(x + t * 8);
  float4 vb = *(const float4*)(x + t * 8 + 4);
  float s  = va.x + va.y + va.z + va.w + vb.x + vb.y + vb.z + vb.w;
  float ss = va.x*va.x + va.y*va.y + va.z*va.z + va.w*va.w
           + vb.x*vb.x + vb.y*vb.y + vb.z*vb.z + vb.w*vb.w;
  #pragma unroll
  for (int m = 1; m < 64; m <<= 1) { s += __shfl_xor(s, m); ss += __shfl_xor(ss, m); }
  __shared__ float rs[4], rss[4];
  if (lane == 0) { rs[wid] = s; rss[wid] = ss; }
  __syncthreads();
  float st = rs[0] + rs[1] + rs[2] + rs[3];
  float sst = rss[0] + rss[1] + rss[2] + rss[3];
  float mu = st * (1.0f / 2048.0f);
  float var = sst * (1.0f / 2048.0f) - mu * mu;
  float rstd = rsqrtf(var + 1e-6f);
  float4 wa = *(const float4*)(w + t * 8);
  float4 wb = *(const float4*)(w + t * 8 + 4);
  float4 ba = *(const float4*)(bb + t * 8);
  float4 bb4 = *(const float4*)(bb + t * 8 + 4);
  bf16x8 ov;
  ov[0] = f2bf((va.x - mu) * rstd * wa.x + ba.x);
  ov[1] = f2bf((va.y - mu) * rstd * wa.y + ba.y);
  ov[2] = f2bf((va.z - mu) * rstd * wa.z + ba.z);
  ov[3] = f2bf((va.w - mu) * rstd * wa.w + ba.w);
  ov[4] = f2bf((vb.x - mu) * rstd * wb.x + bb4.x);
  ov[5] = f2bf((vb.y - mu) * rstd * wb.y + bb4.y);
  ov[6] = f2bf((vb.z - mu) * rstd * wb.z + bb4.z);
  ov[7] = f2bf((vb.w - mu) * rstd * wb.w + bb4.w);
  *(bf16x8*)(o + t * 8) = ov;
}

// ======== 8-phase 256x256 BT-GEMM with LONG-LEAD staging (round-8 best) ====
template <int EPI>
__global__ __launch_bounds__(512, 2) void gemm256(
    const bf16_t* __restrict__ A, const bf16_t* __restrict__ B,
    void* __restrict__ C, void* __restrict__ C2,
    const float* __restrict__ gatep,
    int Mreal, int N, int K, int nnt) {
  __shared__ bf16_t As[2][256 * 64];
  __shared__ bf16_t Bs[2][256 * 64];
  const int nblk = gridDim.x;
  const int orig = blockIdx.x;
  const int qd = nblk >> 3, rr = nblk & 7, xc = orig & 7, lin = orig >> 3;
  const int wg = (xc < rr ? xc * (qd + 1) : rr * (qd + 1) + (xc - rr) * qd) + lin;
  const int mtile = wg / nnt, ntile = wg - mtile * nnt;
  const int m0 = mtile * 256, n0 = ntile * 256;

  const int tid = threadIdx.x;
  const int wid = tid >> 6, lane = tid & 63;
  const int l15 = lane & 15, l4 = lane >> 4;
  const int wr = wid >> 2, wc = wid & 3;     // wave grid 2M x 4N
  const int srow = lane >> 3;
  const int scol = 8 * ((lane & 7) ^ srow);  // pre-swizzled source col (elems)

  f32x4v acc[8][4] = {};
  const int NKT = K >> 6;

  auto gload = [&](const bf16_t* g, bf16_t* l) {
    __builtin_amdgcn_global_load_lds((const __attribute__((address_space(1))) unsigned int*)g,
        (__attribute__((address_space(3))) unsigned int*)l, 16, 0, 0);
  };
  auto stageA4 = [&](int kt) {
    bf16_t* an = As[kt & 1];
    const int k0 = kt << 6;
    #pragma unroll
    for (int q = 0; q < 4; ++q) {
      int chunk = wr * 16 + wc * 4 + q;
      int row = chunk * 8 + srow;
      gload(A + (size_t)(m0 + row) * K + k0 + scol, an + chunk * 512);
    }
  };
  auto stageB4 = [&](int kt) {
    bf16_t* bn = Bs[kt & 1];
    const int k0 = kt << 6;
    #pragma unroll
    for (int q = 0; q < 4; ++q) {
      int chunk = wc * 8 + wr * 4 + q;
      int row = chunk * 8 + srow;
      gload(B + (size_t)(n0 + row) * K + k0 + scol, bn + chunk * 512);
    }
  };
  auto ld_a = [&](const bf16_t* as, int ks, int mi) -> bf16x8 {
    int row = wr * 128 + mi * 16 + l15;
    int cb = ks * 64 + l4 * 16;
    return *(const bf16x8*)((const char*)as + row * 128 + (cb ^ ((row & 7) << 4)));
  };
  auto ld_b = [&](const bf16_t* bs, int ks, int ni) -> bf16x8 {
    int row = wc * 64 + ni * 16 + l15;
    int cb = ks * 64 + l4 * 16;
    return *(const bf16x8*)((const char*)bs + row * 128 + (cb ^ ((row & 7) << 4)));
  };

  stageA4(0); stageB4(0); stageA4(1);
  asm volatile("s_waitcnt vmcnt(4)" ::: "memory");
  __builtin_amdgcn_s_barrier();

  for (int t = 0; t < NKT; ++t) {
    const bf16_t* as = As[t & 1];
    const bf16_t* bs = Bs[t & 1];
    bf16x8 afr[8], bfr[2];

    #pragma unroll
    for (int mi = 0; mi < 8; ++mi) afr[mi] = ld_a(as, 0, mi);
    bfr[0] = ld_b(bs, 0, 0); bfr[1] = ld_b(bs, 0, 1);
    if (t + 1 < NKT) stageB4(t + 1);
    __builtin_amdgcn_s_barrier();
    asm volatile("s_waitcnt lgkmcnt(0)" ::: "memory");
    __builtin_amdgcn_s_setprio(1);
    #pragma unroll
    for (int mi = 0; mi < 8; ++mi) {
      acc[mi][0] = __builtin_amdgcn_mfma_f32_16x16x32_bf16(afr[mi], bfr[0], acc[mi][0], 0, 0, 0);
      acc[mi][1] = __builtin_amdgcn_mfma_f32_16x16x32_bf16(afr[mi], bfr[1], acc[mi][1], 0, 0, 0);
    }
    __builtin_amdgcn_s_setprio(0);
    __builtin_amdgcn_s_barrier();

    bfr[0] = ld_b(bs, 0, 2); bfr[1] = ld_b(bs, 0, 3);
    __builtin_amdgcn_s_barrier();
    asm volatile("s_waitcnt lgkmcnt(0)" ::: "memory");
    __builtin_amdgcn_s_setprio(1);
    #pragma unroll
    for (int mi = 0; mi < 8; ++mi) {
      acc[mi][2] = __builtin_amdgcn_mfma_f32_16x16x32_bf16(afr[mi], bfr[0], acc[mi][2], 0, 0, 0);
      acc[mi][3] = __builtin_amdgcn_mfma_f32_16x16x32_bf16(afr[mi], bfr[1], acc[mi][3], 0, 0, 0);
    }
    __builtin_amdgcn_s_setprio(0);
    __builtin_amdgcn_s_barrier();

    #pragma unroll
    for (int mi = 0; mi < 8; ++mi) afr[mi] = ld_a(as, 1, mi);
    bfr[0] = ld_b(bs, 1, 0); bfr[1] = ld_b(bs, 1, 1);
    __builtin_amdgcn_s_barrier();
    asm volatile("s_waitcnt lgkmcnt(0)" ::: "memory");
    __builtin_amdgcn_s_setprio(1);
    #pragma unroll
    for (int mi = 0; mi < 8; ++mi) {
      acc[mi][0] = __builtin_amdgcn_mfma_f32_16x16x32_bf16(afr[mi], bfr[0], acc[mi][0], 0, 0, 0);
      acc[mi][1] = __builtin_amdgcn_mfma_f32_16x16x32_bf16(afr[mi], bfr[1], acc[mi][1], 0, 0, 0);
    }
    __builtin_amdgcn_s_setprio(0);
    __builtin_amdgcn_s_barrier();

    bfr[0] = ld_b(bs, 1, 2); bfr[1] = ld_b(bs, 1, 3);
    if (t + 2 < NKT) stageA4(t + 2);
    __builtin_amdgcn_s_barrier();
    asm volatile("s_waitcnt lgkmcnt(0)" ::: "memory");
    __builtin_amdgcn_s_setprio(1);
    #pragma unroll
    for (int mi = 0; mi < 8; ++mi) {
      acc[mi][2] = __builtin_amdgcn_mfma_f32_16x16x32_bf16(afr[mi], bfr[0], acc[mi][2], 0, 0, 0);
      acc[mi][3] = __builtin_amdgcn_mfma_f32_16x16x32_bf16(afr[mi], bfr[1], acc[mi][3], 0, 0, 0);
    }
    __builtin_amdgcn_s_setprio(0);
    if (t + 2 < NKT)      asm volatile("s_waitcnt vmcnt(4)" ::: "memory");
    else if (t + 1 < NKT) asm volatile("s_waitcnt vmcnt(0)" ::: "memory");
    __builtin_amdgcn_s_barrier();
  }

  float scale = 1.0f;
  if (EPI == 2) scale = tanhf(gatep[0]);
  bf16_t* Cb = (bf16_t*)C;
  int colbase = n0;
  int ldc = N;
  if (EPI == 3) {
    ldc = 2048;
    if (n0 >= 2048) { Cb = (bf16_t*)C2; colbase = n0 - 2048; }
  }
  #pragma unroll
  for (int mi = 0; mi < 8; ++mi) {
    #pragma unroll
    for (int ni = 0; ni < 4; ++ni) {
      int c = colbase + wc * 64 + ni * 16 + l15;
      #pragma unroll
      for (int j = 0; j < 4; ++j) {
        int r = m0 + wr * 128 + mi * 16 + 4 * l4 + j;
        if (r >= Mreal) continue;
        float v = acc[mi][ni][j];
        if (EPI == 2) ((float*)C)[(size_t)r * N + c] = v * scale;
        else Cb[(size_t)r * ldc + c] = f2bf(v);
      }
    }
  }
}

// ---- 128x128 BT-GEMM (round-2 proven) for the small importance GEMM ----
template <int EPI>
__global__ __launch_bounds__(256, 2) void gemm_bt(
    const bf16_t* __restrict__ A, const bf16_t* __restrict__ B,
    void* __restrict__ C, void* __restrict__ C2,
    const float* __restrict__ bias, const float* __restrict__ gatep,
    int M, int N, int K, int nnt) {
  __shared__ bf16_t As[2][128 * 64];
  __shared__ bf16_t Bs[2][128 * 64];
  const int nblk = gridDim.x;
  const int orig = blockIdx.x;
  const int qd = nblk >> 3, rr = nblk & 7, xc = orig & 7, lin = orig >> 3;
  const int wg = (xc < rr ? xc * (qd + 1) : rr * (qd + 1) + (xc - rr) * qd) + lin;
  const int mtile = wg / nnt;
  const int ntile = wg - mtile * nnt;
  const int m0 = mtile * 128, n0 = ntile * 128;

  const int tid = threadIdx.x;
  const int wid = tid >> 6, lane = tid & 63;
  const int l15 = lane & 15, l4 = lane >> 4;
  const int wm = (wid >> 1) * 64, wn = (wid & 1) * 64;
  const int srow = lane >> 3;
  const int scol = 8 * ((lane & 7) ^ (lane >> 3));

  f32x4v acc[4][4] = {};
  const int nkt = K >> 6;

  auto stage = [&](int kt, int buf) {
    const int k0 = kt << 6;
    #pragma unroll
    for (int it = 0; it < 4; ++it) {
      int chunk = wid + 4 * it;  // 0..15
      int row = chunk * 8 + srow;
      const bf16_t* ga = A + (size_t)(m0 + row) * K + k0 + scol;
      const bf16_t* gb = B + (size_t)(n0 + row) * K + k0 + scol;
      bf16_t* la = &As[buf][chunk * 512];
      bf16_t* lb = &Bs[buf][chunk * 512];
      __builtin_amdgcn_global_load_lds((const __attribute__((address_space(1))) unsigned int*)ga,
                                       (__attribute__((address_space(3))) unsigned int*)la, 16, 0, 0);
      __builtin_amdgcn_global_load_lds((const __attribute__((address_space(1))) unsigned int*)gb,
                                       (__attribute__((address_space(3))) unsigned int*)lb, 16, 0, 0);
    }
  };

  stage(0, 0);
  for (int kt = 0; kt < nkt; ++kt) {
    int buf = kt & 1;
    __syncthreads();
    if (kt + 1 < nkt) stage(kt + 1, buf ^ 1);
    const char* as = (const char*)As[buf];
    const char* bs = (const char*)Bs[buf];
    #pragma unroll
    for (int ki = 0; ki < 2; ++ki) {
      int cb = ki * 64 + l4 * 16;
      bf16x8 af[4], bfv[4];
      #pragma unroll
      for (int mi = 0; mi < 4; ++mi) {
        int row = wm + mi * 16 + l15;
        af[mi] = *(const bf16x8*)(as + row * 128 + (cb ^ ((row & 7) << 4)));
      }
      #pragma unroll
      for (int ni = 0; ni < 4; ++ni) {
        int row = wn + ni * 16 + l15;
        bfv[ni] = *(const bf16x8*)(bs + row * 128 + (cb ^ ((row & 7) << 4)));
      }
      #pragma unroll
      for (int mi = 0; mi < 4; ++mi)
        #pragma unroll
        for (int ni = 0; ni < 4; ++ni)
          acc[mi][ni] = __builtin_amdgcn_mfma_f32_16x16x32_bf16(af[mi], bfv[ni], acc[mi][ni], 0, 0, 0);
    }
    __syncthreads();
  }

  #pragma unroll
  for (int mi = 0; mi < 4; ++mi) {
    #pragma unroll
    for (int ni = 0; ni < 4; ++ni) {
      int c = n0 + wn + ni * 16 + l15;
      #pragma unroll
      for (int j = 0; j < 4; ++j) {
        int r = m0 + wm + mi * 16 + 4 * l4 + j;
        float v = acc[mi][ni][j];
        if (EPI == 1) { v += bias[c]; v = v > 0.0f ? v : 0.0f; }
        ((bf16_t*)C)[(size_t)r * N + c] = f2bf(v);
      }
    }
  }
}

// ---------------- gate_score = sigmoid(semLN @ gate_w^T + gate_b) ----------
__global__ __launch_bounds__(256) void gate_kernel(const bf16_t* __restrict__ a,
                                                   const float* __restrict__ gw,
                                                   const float* __restrict__ gb,
                                                   float* __restrict__ gs) {
  int r0 = blockIdx.x * 4;
  int t = threadIdx.x;
  int j = t >> 5, lt = t & 31;
  const float* wr = gw + (size_t)j * DMODEL;
  float sum[4] = {0.0f, 0.0f, 0.0f, 0.0f};
  #pragma unroll
  for (int u = 0; u < 8; ++u) {
    int i = lt * 8 + u * 256;
    float4 w0 = *(const float4*)(wr + i);
    float4 w1 = *(const float4*)(wr + i + 4);
    #pragma unroll
    for (int r = 0; r < 4; ++r) {
      bf16x8 av = *(const bf16x8*)(a + (size_t)(r0 + r) * DMODEL + i);
      sum[r] += bf2f(av[0]) * w0.x + bf2f(av[1]) * w0.y + bf2f(av[2]) * w0.z + bf2f(av[3]) * w0.w
              + bf2f(av[4]) * w1.x + bf2f(av[5]) * w1.y + bf2f(av[6]) * w1.z + bf2f(av[7]) * w1.w;
    }
  }
  #pragma unroll
  for (int m = 1; m < 32; m <<= 1) {
    #pragma unroll
    for (int r = 0; r < 4; ++r) sum[r] += __shfl_xor(sum[r], m);
  }
  if (lt == 0) {
    #pragma unroll
    for (int r = 0; r < 4; ++r)
      gs[(size_t)(r0 + r) * 8 + j] = 1.0f / (1.0f + __expf(-(sum[r] + gb[j])));
  }
}

// ------------- key bias = log(sigmoid(hidden @ w2^T + b2) + 0.1) ----------
__global__ __launch_bounds__(256) void imp_kernel(const bf16_t* __restrict__ hid,
                                                  const float* __restrict__ w2,
                                                  const float* __restrict__ b2,
                                                  float* __restrict__ kb) {
  int row = blockIdx.x * 4 + (threadIdx.x >> 6);
  int lane = threadIdx.x & 63;
  const bf16_t* hr = hid + (size_t)row * 512;
  bf16x8 hv = *(const bf16x8*)(hr + lane * 8);
  float sum = 0.0f;
  #pragma unroll
  for (int i = 0; i < 8; ++i) sum += bf2f(hv[i]) * w2[lane * 8 + i];
  #pragma unroll
  for (int m = 1; m < 64; m <<= 1) sum += __shfl_xor(sum, m);
  if (lane == 0) {
    float imp = 1.0f / (1.0f + __expf(-(sum + b2[0])));
    kb[row] = logf(imp + 0.1f);
  }
}

// ---------------- attention (round-8 best-known) --------------------------
__global__ __launch_bounds__(512, 1) void attn_kernel(
    const bf16_t* __restrict__ Q, const bf16_t* __restrict__ K,
    const bf16_t* __restrict__ V, const float* __restrict__ gs,
    const float* __restrict__ kb, bf16_t* __restrict__ O) {
  __shared__ bf16_t Kt[64 * 128];       // [key][d] swizzled
  __shared__ bf16_t Vt[128 * 64];       // [d][key] swizzled
  __shared__ bf16_t Pl[8][32 * 72];     // per-wave P scratch
  __shared__ float kyf[256], kxf[256], kbl[256];

  const int bi = blockIdx.x >> 4;
  const int h = blockIdx.x & 15;
  const int tid = threadIdx.x;
  const int wid = tid >> 6;
  const int lane = tid & 63;
  const int l15 = lane & 15, l4 = lane >> 4;
  const bool hs = (h < 8);

  for (int i = tid; i < 256; i += 512) {
    kyf[i] = (float)(i / 18);
    kxf[i] = (float)(i % 18);
    int kk = i < SEQ ? i : SEQ - 1;
    kbl[i] = kb[bi * SEQ + kk];
  }

  const int q0 = wid * 32;
  bf16x8 qf[2][4];
  #pragma unroll
  for (int mi = 0; mi < 2; ++mi) {
    int q = q0 + mi * 16 + l15; if (q >= SEQ) q = SEQ - 1;
    const bf16_t* qp = Q + (size_t)(bi * SEQ + q) * DMODEL + h * HDIM;
    #pragma unroll
    for (int ki = 0; ki < 4; ++ki) qf[mi][ki] = *(const bf16x8*)(qp + ki * 32 + l4 * 8);
  }

  const float invdiag = 1.0f / (sqrtf(520.0f) + 1e-6f);
  float gsd[2][4], qyv[2][4], qxv[2][4];
  #pragma unroll
  for (int mi = 0; mi < 2; ++mi)
    #pragma unroll
    for (int j = 0; j < 4; ++j) {
      int q = q0 + mi * 16 + 4 * l4 + j;
      int qc = q < SEQ ? q : SEQ - 1;
      gsd[mi][j] = hs ? gs[(size_t)(bi * SEQ + qc) * 8 + h] * invdiag : 0.0f;
      qyv[mi][j] = (float)(q / 18);
      qxv[mi][j] = (float)(q % 18);
    }

  f32x4v oacc[2][8] = {};
  f32x4v osum[2] = {};
  const float scl = 0.08838834764831845f;       // 1/sqrt(128)
  bf16_t* Plw = &Pl[wid][0];
  bf16x8 vones;
  #pragma unroll
  for (int i = 0; i < 8; ++i) vones[i] = f2bf(1.0f);

  for (int t = 0; t < 4; ++t) {
    __syncthreads();
    #pragma unroll
    for (int rep = 0; rep < 2; ++rep) {
      int s = tid + rep * 512;
      int row = s >> 4, cb = s & 15;
      int kk = t * 64 + row;
      uint4 val = make_uint4(0, 0, 0, 0);
      if (kk < SEQ) val = *(const uint4*)(K + (size_t)(bi * SEQ + kk) * DMODEL + h * HDIM + cb * 8);
      *(uint4*)((char*)Kt + row * 256 + ((cb * 16) ^ ((row & 7) << 4))) = val;
    }
    {
      int kp = tid >> 4, db = tid & 15;
      int k0i = t * 64 + kp * 2, k1i = k0i + 1;
      uint4 a = make_uint4(0, 0, 0, 0), c4 = make_uint4(0, 0, 0, 0);
      if (k0i < SEQ) a = *(const uint4*)(V + (size_t)(bi * SEQ + k0i) * DMODEL + h * HDIM + db * 8);
      if (k1i < SEQ) c4 = *(const uint4*)(V + (size_t)(bi * SEQ + k1i) * DMODEL + h * HDIM + db * 8);
      const ushort_t* au = (const ushort_t*)&a;
      const ushort_t* cu = (const ushort_t*)&c4;
      #pragma unroll
      for (int i = 0; i < 8; ++i) {
        int d = db * 8 + i;
        unsigned pv = (unsigned)au[i] | ((unsigned)cu[i] << 16);
        *(unsigned*)((char*)Vt + d * 128 + ((kp * 4) ^ ((d & 7) << 4))) = pv;
      }
    }
    __syncthreads();

    f32x4v sc[2][4] = {};
    #pragma unroll
    for (int ki = 0; ki < 4; ++ki) {
      bf16x8 kf[4];
      #pragma unroll
      for (int ni = 0; ni < 4; ++ni) {
        int row = ni * 16 + l15;
        kf[ni] = *(const bf16x8*)((char*)Kt + row * 256 + ((ki * 64 + l4 * 16) ^ ((row & 7) << 4)));
      }
      #pragma unroll
      for (int mi = 0; mi < 2; ++mi)
        #pragma unroll
        for (int ni = 0; ni < 4; ++ni)
          sc[mi][ni] = __builtin_amdgcn_mfma_f32_16x16x32_bf16(qf[mi][ki], kf[ni], sc[mi][ni], 0, 0, 0);
    }

    #pragma unroll
    for (int mi = 0; mi < 2; ++mi) {
      #pragma unroll
      for (int j = 0; j < 4; ++j) {
        int prow = mi * 16 + 4 * l4 + j;
        #pragma unroll
        for (int ni = 0; ni < 4; ++ni) {
          int kk = t * 64 + ni * 16 + l15;
          float s = sc[mi][ni][j] * scl + kbl[kk];
          if (hs) {
            float dy = qyv[mi][j] - kyf[kk];
            float dx = qxv[mi][j] - kxf[kk];
            s -= sqrtf(dy * dy + dx * dx) * gsd[mi][j];
          }
          float p = (kk < SEQ) ? __expf(s) : 0.0f;
          Plw[prow * 72 + ni * 16 + l15] = f2bf(p);
        }
      }
    }

    #pragma unroll
    for (int ks = 0; ks < 2; ++ks) {
      bf16x8 pf[2];
      #pragma unroll
      for (int mi = 0; mi < 2; ++mi)
        pf[mi] = *(const bf16x8*)(Plw + (mi * 16 + l15) * 72 + ks * 32 + l4 * 8);
      #pragma unroll
      for (int mi = 0; mi < 2; ++mi)
        osum[mi] = __builtin_amdgcn_mfma_f32_16x16x32_bf16(pf[mi], vones, osum[mi], 0, 0, 0);
      #pragma unroll
      for (int di = 0; di < 8; ++di) {
        int d = di * 16 + l15;
        bf16x8 vf = *(const bf16x8*)((char*)Vt + d * 128 + ((ks * 64 + l4 * 16) ^ ((d & 7) << 4)));
        #pragma unroll
        for (int mi = 0; mi < 2; ++mi)
          oacc[mi][di] = __builtin_amdgcn_mfma_f32_16x16x32_bf16(pf[mi], vf, oacc[mi][di], 0, 0, 0);
      }
    }
  }

  #pragma unroll
  for (int mi = 0; mi < 2; ++mi) {
    #pragma unroll
    for (int j = 0; j < 4; ++j) {
      int q = q0 + mi * 16 + 4 * l4 + j;
      if (q >= SEQ) continue;
      float inv = 1.0f / osum[mi][j];
      bf16_t* op = O + (size_t)(bi * SEQ + q) * DMODEL + h * HDIM;
      #pragma unroll
      for (int di = 0; di < 8; ++di)
        op[di * 16 + l15] = f2bf(oacc[mi][di][j] * inv);
    }
  }
}

// --------------------------------------------------------------------------
extern "C" void kernel_launch(void* const* d_in, const int* in_sizes, int n_in,
                              void* d_out, int out_size, void* d_ws, size_t ws_size,
                              hipStream_t stream) {
  const float* sem  = (const float*)d_in[0];
  const float* vgg  = (const float*)d_in[1];
  const float* ln1w = (const float*)d_in[3];
  const float* ln1b = (const float*)d_in[4];
  const float* ln2w = (const float*)d_in[5];
  const float* ln2b = (const float*)d_in[6];
  const float* Wq   = (const float*)d_in[7];
  const float* Wk   = (const float*)d_in[8];
  const float* Wv   = (const float*)d_in[9];
  const float* Wo   = (const float*)d_in[10];
  const float* w1   = (const float*)d_in[11];
  const float* b1   = (const float*)d_in[12];
  const float* w2   = (const float*)d_in[13];
  const float* b2   = (const float*)d_in[14];
  const float* gw   = (const float*)d_in[15];
  const float* gb   = (const float*)d_in[16];
  const float* gate = (const float*)d_in[17];

  char* ws = (char*)d_ws;
  const size_t SZ_W    = 8388608;    // 2048*2048*2
  const size_t SZ_PAD  = 33554432;   // 8192*2048*2 (padded activations, A-side)
  const size_t SZ_ACT  = 33030144;   // 8064*2048*2
  bf16_t* Wqb  = (bf16_t*)(ws + 0);
  bf16_t* Wkb  = (bf16_t*)(ws + SZ_W);       // Wk;Wv contiguous = fused KV weight
  bf16_t* Wvb  = (bf16_t*)(ws + 2 * SZ_W);
  bf16_t* Wob  = (bf16_t*)(ws + 3 * SZ_W);
  bf16_t* w1b  = (bf16_t*)(ws + 4 * SZ_W);                     // 2 MB
  bf16_t* semb = (bf16_t*)(ws + 4 * SZ_W + 2097152);           // padded; attn-out alias
  bf16_t* vggb = (bf16_t*)(ws + 4 * SZ_W + 2097152 + SZ_PAD);  // padded
  bf16_t* Vb   = (bf16_t*)(ws + 4 * SZ_W + 2097152 + 2 * SZ_PAD);
  bf16_t* hidb = (bf16_t*)(ws + 4 * SZ_W + 2097152 + 2 * SZ_PAD + SZ_ACT);
  float*  gsb  = (float*)(ws + 4 * SZ_W + 2097152 + 2 * SZ_PAD + SZ_ACT + 8257536);
  float*  kbb  = (float*)(ws + 4 * SZ_W + 2097152 + 2 * SZ_PAD + SZ_ACT + 8257536 + 258048);
  // Q and K (8064 rows each, bf16) exactly fill d_out (8064*2048*4 B)
  bf16_t* Qb = (bf16_t*)d_out;
  bf16_t* Kb = (bf16_t*)((char*)d_out + SZ_ACT);
  bf16_t* attnb = semb;

  cvt5_kernel<<<dim3(2048, 5), 256, 0, stream>>>(Wq, Wk, Wv, Wo, w1,
                                                 Wqb, Wkb, Wvb, Wob, w1b);
  ln_kernel<<<dim3(8064, 2), 256, 0, stream>>>(sem, vgg, ln1w, ln1b, ln2w, ln2b, semb, vggb);

  // Q projection: 8192(pad)x2048x2048
  gemm256<0><<<256, 512, 0, stream>>>(semb, Wqb, Qb, nullptr, nullptr,
                                      8064, 2048, 2048, 8);
  // fused K+V projection: 8192(pad)x4096x2048 (Wk;Wv adjacent)
  gemm256<3><<<512, 512, 0, stream>>>(vggb, Wkb, Kb, Vb, nullptr,
                                      8064, 4096, 2048, 16);
  // importance hidden: 8064x512x2048, relu+bias (128^2 kernel)
  gemm_bt<1><<<252, 256, 0, stream>>>(semb, w1b, hidb, nullptr, b1, nullptr,
                                      8064, 512, 2048, 4);

  gate_kernel<<<2016, 256, 0, stream>>>(semb, gw, gb, gsb);
  imp_kernel<<<2016, 256, 0, stream>>>(hidb, w2, b2, kbb);

  attn_kernel<<<512, 512, 0, stream>>>(Qb, Kb, Vb, gsb, kbb, attnb);

  // output projection: 8192(pad)x2048x2048, *tanh(gate), f32 out
  gemm256<2><<<256, 512, 0, stream>>>(attnb, Wob, d_out, nullptr, gate,
                                      8064, 2048, 2048, 8);
}

// Round 13
// 466.830 us; speedup vs baseline: 1.1043x; 1.0165x over previous
//
#include <hip/hip_runtime.h>
#include <hip/hip_bf16.h>
#include <math.h>

typedef __bf16 bf16_t;
typedef __bf16 bf16x8 __attribute__((ext_vector_type(8)));
typedef float f32x4v __attribute__((ext_vector_type(4)));
typedef unsigned short ushort_t;

#define SL_TOTAL 8064
#define SL_PAD 8192
#define DMODEL 2048
#define NHEAD 16
#define HDIM 128
#define SEQ 252

__device__ __forceinline__ bf16_t f2bf(float f) {
  unsigned u = __builtin_bit_cast(unsigned, f);
  u += 0x7fffu + ((u >> 16) & 1u);
  ushort_t h = (ushort_t)(u >> 16);
  return __builtin_bit_cast(bf16_t, h);
}
__device__ __forceinline__ float bf2f(bf16_t b) {
  unsigned u = ((unsigned)__builtin_bit_cast(ushort_t, b)) << 16;
  return __builtin_bit_cast(float, u);
}

// ---------------- fused 4-weight f32 -> bf16 convert ----------------
__global__ __launch_bounds__(256) void cvt4_kernel(const float* __restrict__ s0,
                                                   const float* __restrict__ s1,
                                                   const float* __restrict__ s2,
                                                   const float* __restrict__ s3,
                                                   bf16_t* __restrict__ d0,
                                                   bf16_t* __restrict__ d1,
                                                   bf16_t* __restrict__ d2,
                                                   bf16_t* __restrict__ d3) {
  const float* src; bf16_t* dst;
  switch (blockIdx.y) {
    case 0: src = s0; dst = d0; break;
    case 1: src = s1; dst = d1; break;
    case 2: src = s2; dst = d2; break;
    default: src = s3; dst = d3; break;
  }
  int i = (blockIdx.x * 256 + threadIdx.x) * 8;
  float4 a = *(const float4*)(src + i);
  float4 b = *(const float4*)(src + i + 4);
  bf16x8 o;
  o[0] = f2bf(a.x); o[1] = f2bf(a.y); o[2] = f2bf(a.z); o[3] = f2bf(a.w);
  o[4] = f2bf(b.x); o[5] = f2bf(b.y); o[6] = f2bf(b.z); o[7] = f2bf(b.w);
  *(bf16x8*)(dst + i) = o;
}

__global__ __launch_bounds__(256) void cvt_kernel(const float* __restrict__ src,
                                                  bf16_t* __restrict__ dst, int n) {
  int i = (blockIdx.x * 256 + threadIdx.x) * 8;
  if (i >= n) return;
  float4 a = *(const float4*)(src + i);
  float4 b = *(const float4*)(src + i + 4);
  bf16x8 o;
  o[0] = f2bf(a.x); o[1] = f2bf(a.y); o[2] = f2bf(a.z); o[3] = f2bf(a.w);
  o[4] = f2bf(b.x); o[5] = f2bf(b.y); o[6] = f2bf(b.z); o[7] = f2bf(b.w);
  *(bf16x8*)(dst + i) = o;
}

// ---------------- fused dual LayerNorm (f32 in, bf16 out) ----------------
__global__ __launch_bounds__(256) void ln_kernel(
    const float* __restrict__ sem, const float* __restrict__ vgg,
    const float* __restrict__ w1, const float* __restrict__ b1,
    const float* __restrict__ w2, const float* __restrict__ b2,
    bf16_t* __restrict__ o1, bf16_t* __restrict__ o2) {
  const float* x; const float* w; const float* bb; bf16_t* o;
  int row = blockIdx.x;
  if (blockIdx.y == 0) { x = sem; w = w1; bb = b1; o = o1; }
  else                 { x = vgg; w = w2; bb = b2; o = o2; }
  x += (size_t)row * DMODEL; o += (size_t)row * DMODEL;
  int t = threadIdx.x, wid = t >> 6, lane = t & 63;
  float4 va = *(const float4*)(x + t * 8);
  float4 vb = *(const float4*)(x + t * 8 + 4);
  float s  = va.x + va.y + va.z + va.w + vb.x + vb.y + vb.z + vb.w;
  float ss = va.x*va.x + va.y*va.y + va.z*va.z + va.w*va.w
           + vb.x*vb.x + vb.y*vb.y + vb.z*vb.z + vb.w*vb.w;
  #pragma unroll
  for (int m = 1; m < 64; m <<= 1) { s += __shfl_xor(s, m); ss += __shfl_xor(ss, m); }
  __shared__ float rs[4], rss[4];
  if (lane == 0) { rs[wid] = s; rss[wid] = ss; }
  __syncthreads();
  float st = rs[0] + rs[1] + rs[2] + rs[3];
  float sst = rss[0] + rss[1] + rss[2] + rss[3];
  float mu = st * (1.0f / 2048.0f);
  float var = sst * (1.0f / 2048.0f) - mu * mu;
  float rstd = rsqrtf(var + 1e-6f);
  float4 wa = *(const float4*)(w + t * 8);
  float4 wb = *(const float4*)(w + t * 8 + 4);
  float4 ba = *(const float4*)(bb + t * 8);
  float4 bb4 = *(const float4*)(bb + t * 8 + 4);
  bf16x8 ov;
  ov[0] = f2bf((va.x - mu) * rstd * wa.x + ba.x);
  ov[1] = f2bf((va.y - mu) * rstd * wa.y + ba.y);
  ov[2] = f2bf((va.z - mu) * rstd * wa.z + ba.z);
  ov[3] = f2bf((va.w - mu) * rstd * wa.w + ba.w);
  ov[4] = f2bf((vb.x - mu) * rstd * wb.x + bb4.x);
  ov[5] = f2bf((vb.y - mu) * rstd * wb.y + bb4.y);
  ov[6] = f2bf((vb.z - mu) * rstd * wb.z + bb4.z);
  ov[7] = f2bf((vb.w - mu) * rstd * wb.w + bb4.w);
  *(bf16x8*)(o + t * 8) = ov;
}

// ======== 8-phase 256x256 BT-GEMM with LONG-LEAD staging (session best) ====
template <int EPI>
__global__ __launch_bounds__(512, 2) void gemm256(
    const bf16_t* __restrict__ A, const bf16_t* __restrict__ B,
    void* __restrict__ C, void* __restrict__ C2,
    const float* __restrict__ gatep,
    int Mreal, int N, int K, int nnt) {
  __shared__ bf16_t As[2][256 * 64];
  __shared__ bf16_t Bs[2][256 * 64];
  const int nblk = gridDim.x;
  const int orig = blockIdx.x;
  const int qd = nblk >> 3, rr = nblk & 7, xc = orig & 7, lin = orig >> 3;
  const int wg = (xc < rr ? xc * (qd + 1) : rr * (qd + 1) + (xc - rr) * qd) + lin;
  const int mtile = wg / nnt, ntile = wg - mtile * nnt;
  const int m0 = mtile * 256, n0 = ntile * 256;

  const int tid = threadIdx.x;
  const int wid = tid >> 6, lane = tid & 63;
  const int l15 = lane & 15, l4 = lane >> 4;
  const int wr = wid >> 2, wc = wid & 3;     // wave grid 2M x 4N
  const int srow = lane >> 3;
  const int scol = 8 * ((lane & 7) ^ srow);  // pre-swizzled source col (elems)

  f32x4v acc[8][4] = {};
  const int NKT = K >> 6;

  auto gload = [&](const bf16_t* g, bf16_t* l) {
    __builtin_amdgcn_global_load_lds((const __attribute__((address_space(1))) unsigned int*)g,
        (__attribute__((address_space(3))) unsigned int*)l, 16, 0, 0);
  };
  auto stageA4 = [&](int kt) {
    bf16_t* an = As[kt & 1];
    const int k0 = kt << 6;
    #pragma unroll
    for (int q = 0; q < 4; ++q) {
      int chunk = wr * 16 + wc * 4 + q;
      int row = chunk * 8 + srow;
      gload(A + (size_t)(m0 + row) * K + k0 + scol, an + chunk * 512);
    }
  };
  auto stageB4 = [&](int kt) {
    bf16_t* bn = Bs[kt & 1];
    const int k0 = kt << 6;
    #pragma unroll
    for (int q = 0; q < 4; ++q) {
      int chunk = wc * 8 + wr * 4 + q;
      int row = chunk * 8 + srow;
      gload(B + (size_t)(n0 + row) * K + k0 + scol, bn + chunk * 512);
    }
  };
  auto ld_a = [&](const bf16_t* as, int ks, int mi) -> bf16x8 {
    int row = wr * 128 + mi * 16 + l15;
    int cb = ks * 64 + l4 * 16;
    return *(const bf16x8*)((const char*)as + row * 128 + (cb ^ ((row & 7) << 4)));
  };
  auto ld_b = [&](const bf16_t* bs, int ks, int ni) -> bf16x8 {
    int row = wc * 64 + ni * 16 + l15;
    int cb = ks * 64 + l4 * 16;
    return *(const bf16x8*)((const char*)bs + row * 128 + (cb ^ ((row & 7) << 4)));
  };

  stageA4(0); stageB4(0); stageA4(1);
  asm volatile("s_waitcnt vmcnt(4)" ::: "memory");
  __builtin_amdgcn_s_barrier();

  for (int t = 0; t < NKT; ++t) {
    const bf16_t* as = As[t & 1];
    const bf16_t* bs = Bs[t & 1];
    bf16x8 afr[8], bfr[2];

    #pragma unroll
    for (int mi = 0; mi < 8; ++mi) afr[mi] = ld_a(as, 0, mi);
    bfr[0] = ld_b(bs, 0, 0); bfr[1] = ld_b(bs, 0, 1);
    if (t + 1 < NKT) stageB4(t + 1);
    __builtin_amdgcn_s_barrier();
    asm volatile("s_waitcnt lgkmcnt(0)" ::: "memory");
    __builtin_amdgcn_s_setprio(1);
    #pragma unroll
    for (int mi = 0; mi < 8; ++mi) {
      acc[mi][0] = __builtin_amdgcn_mfma_f32_16x16x32_bf16(afr[mi], bfr[0], acc[mi][0], 0, 0, 0);
      acc[mi][1] = __builtin_amdgcn_mfma_f32_16x16x32_bf16(afr[mi], bfr[1], acc[mi][1], 0, 0, 0);
    }
    __builtin_amdgcn_s_setprio(0);
    __builtin_amdgcn_s_barrier();

    bfr[0] = ld_b(bs, 0, 2); bfr[1] = ld_b(bs, 0, 3);
    __builtin_amdgcn_s_barrier();
    asm volatile("s_waitcnt lgkmcnt(0)" ::: "memory");
    __builtin_amdgcn_s_setprio(1);
    #pragma unroll
    for (int mi = 0; mi < 8; ++mi) {
      acc[mi][2] = __builtin_amdgcn_mfma_f32_16x16x32_bf16(afr[mi], bfr[0], acc[mi][2], 0, 0, 0);
      acc[mi][3] = __builtin_amdgcn_mfma_f32_16x16x32_bf16(afr[mi], bfr[1], acc[mi][3], 0, 0, 0);
    }
    __builtin_amdgcn_s_setprio(0);
    __builtin_amdgcn_s_barrier();

    #pragma unroll
    for (int mi = 0; mi < 8; ++mi) afr[mi] = ld_a(as, 1, mi);
    bfr[0] = ld_b(bs, 1, 0); bfr[1] = ld_b(bs, 1, 1);
    __builtin_amdgcn_s_barrier();
    asm volatile("s_waitcnt lgkmcnt(0)" ::: "memory");
    __builtin_amdgcn_s_setprio(1);
    #pragma unroll
    for (int mi = 0; mi < 8; ++mi) {
      acc[mi][0] = __builtin_amdgcn_mfma_f32_16x16x32_bf16(afr[mi], bfr[0], acc[mi][0], 0, 0, 0);
      acc[mi][1] = __builtin_amdgcn_mfma_f32_16x16x32_bf16(afr[mi], bfr[1], acc[mi][1], 0, 0, 0);
    }
    __builtin_amdgcn_s_setprio(0);
    __builtin_amdgcn_s_barrier();

    bfr[0] = ld_b(bs, 1, 2); bfr[1] = ld_b(bs, 1, 3);
    if (t + 2 < NKT) stageA4(t + 2);
    __builtin_amdgcn_s_barrier();
    asm volatile("s_waitcnt lgkmcnt(0)" ::: "memory");
    __builtin_amdgcn_s_setprio(1);
    #pragma unroll
    for (int mi = 0; mi < 8; ++mi) {
      acc[mi][2] = __builtin_amdgcn_mfma_f32_16x16x32_bf16(afr[mi], bfr[0], acc[mi][2], 0, 0, 0);
      acc[mi][3] = __builtin_amdgcn_mfma_f32_16x16x32_bf16(afr[mi], bfr[1], acc[mi][3], 0, 0, 0);
    }
    __builtin_amdgcn_s_setprio(0);
    if (t + 2 < NKT)      asm volatile("s_waitcnt vmcnt(4)" ::: "memory");
    else if (t + 1 < NKT) asm volatile("s_waitcnt vmcnt(0)" ::: "memory");
    __builtin_amdgcn_s_barrier();
  }

  float scale = 1.0f;
  if (EPI == 2) scale = tanhf(gatep[0]);
  bf16_t* Cb = (bf16_t*)C;
  int colbase = n0;
  int ldc = N;
  if (EPI == 3) {
    ldc = 2048;
    if (n0 >= 2048) { Cb = (bf16_t*)C2; colbase = n0 - 2048; }
  }
  #pragma unroll
  for (int mi = 0; mi < 8; ++mi) {
    #pragma unroll
    for (int ni = 0; ni < 4; ++ni) {
      int c = colbase + wc * 64 + ni * 16 + l15;
      #pragma unroll
      for (int j = 0; j < 4; ++j) {
        int r = m0 + wr * 128 + mi * 16 + 4 * l4 + j;
        if (r >= Mreal) continue;
        float v = acc[mi][ni][j];
        if (EPI == 2) ((float*)C)[(size_t)r * N + c] = v * scale;
        else Cb[(size_t)r * ldc + c] = f2bf(v);
      }
    }
  }
}

// ---- 128x128 BT-GEMM (round-2 proven) for the small importance GEMM ----
template <int EPI>
__global__ __launch_bounds__(256, 2) void gemm_bt(
    const bf16_t* __restrict__ A, const bf16_t* __restrict__ B,
    void* __restrict__ C, void* __restrict__ C2,
    const float* __restrict__ bias, const float* __restrict__ gatep,
    int M, int N, int K, int nnt) {
  __shared__ bf16_t As[2][128 * 64];
  __shared__ bf16_t Bs[2][128 * 64];
  const int nblk = gridDim.x;
  const int orig = blockIdx.x;
  const int qd = nblk >> 3, rr = nblk & 7, xc = orig & 7, lin = orig >> 3;
  const int wg = (xc < rr ? xc * (qd + 1) : rr * (qd + 1) + (xc - rr) * qd) + lin;
  const int mtile = wg / nnt;
  const int ntile = wg - mtile * nnt;
  const int m0 = mtile * 128, n0 = ntile * 128;

  const int tid = threadIdx.x;
  const int wid = tid >> 6, lane = tid & 63;
  const int l15 = lane & 15, l4 = lane >> 4;
  const int wm = (wid >> 1) * 64, wn = (wid & 1) * 64;
  const int srow = lane >> 3;
  const int scol = 8 * ((lane & 7) ^ (lane >> 3));

  f32x4v acc[4][4] = {};
  const int nkt = K >> 6;

  auto stage = [&](int kt, int buf) {
    const int k0 = kt << 6;
    #pragma unroll
    for (int it = 0; it < 4; ++it) {
      int chunk = wid + 4 * it;  // 0..15
      int row = chunk * 8 + srow;
      const bf16_t* ga = A + (size_t)(m0 + row) * K + k0 + scol;
      const bf16_t* gb = B + (size_t)(n0 + row) * K + k0 + scol;
      bf16_t* la = &As[buf][chunk * 512];
      bf16_t* lb = &Bs[buf][chunk * 512];
      __builtin_amdgcn_global_load_lds((const __attribute__((address_space(1))) unsigned int*)ga,
                                       (__attribute__((address_space(3))) unsigned int*)la, 16, 0, 0);
      __builtin_amdgcn_global_load_lds((const __attribute__((address_space(1))) unsigned int*)gb,
                                       (__attribute__((address_space(3))) unsigned int*)lb, 16, 0, 0);
    }
  };

  stage(0, 0);
  for (int kt = 0; kt < nkt; ++kt) {
    int buf = kt & 1;
    __syncthreads();
    if (kt + 1 < nkt) stage(kt + 1, buf ^ 1);
    const char* as = (const char*)As[buf];
    const char* bs = (const char*)Bs[buf];
    #pragma unroll
    for (int ki = 0; ki < 2; ++ki) {
      int cb = ki * 64 + l4 * 16;
      bf16x8 af[4], bfv[4];
      #pragma unroll
      for (int mi = 0; mi < 4; ++mi) {
        int row = wm + mi * 16 + l15;
        af[mi] = *(const bf16x8*)(as + row * 128 + (cb ^ ((row & 7) << 4)));
      }
      #pragma unroll
      for (int ni = 0; ni < 4; ++ni) {
        int row = wn + ni * 16 + l15;
        bfv[ni] = *(const bf16x8*)(bs + row * 128 + (cb ^ ((row & 7) << 4)));
      }
      #pragma unroll
      for (int mi = 0; mi < 4; ++mi)
        #pragma unroll
        for (int ni = 0; ni < 4; ++ni)
          acc[mi][ni] = __builtin_amdgcn_mfma_f32_16x16x32_bf16(af[mi], bfv[ni], acc[mi][ni], 0, 0, 0);
    }
    __syncthreads();
  }

  #pragma unroll
  for (int mi = 0; mi < 4; ++mi) {
    #pragma unroll
    for (int ni = 0; ni < 4; ++ni) {
      int c = n0 + wn + ni * 16 + l15;
      #pragma unroll
      for (int j = 0; j < 4; ++j) {
        int r = m0 + wm + mi * 16 + 4 * l4 + j;
        float v = acc[mi][ni][j];
        if (EPI == 1) { v += bias[c]; v = v > 0.0f ? v : 0.0f; }
        ((bf16_t*)C)[(size_t)r * N + c] = f2bf(v);
      }
    }
  }
}

// ---------------- gate_score = sigmoid(semLN @ gate_w^T + gate_b) ----------
__global__ __launch_bounds__(256) void gate_kernel(const bf16_t* __restrict__ a,
                                                   const float* __restrict__ gw,
                                                   const float* __restrict__ gb,
                                                   float* __restrict__ gs) {
  int r0 = blockIdx.x * 4;
  int t = threadIdx.x;
  int j = t >> 5, lt = t & 31;
  const float* wr = gw + (size_t)j * DMODEL;
  float sum[4] = {0.0f, 0.0f, 0.0f, 0.0f};
  #pragma unroll
  for (int u = 0; u < 8; ++u) {
    int i = lt * 8 + u * 256;
    float4 w0 = *(const float4*)(wr + i);
    float4 w1 = *(const float4*)(wr + i + 4);
    #pragma unroll
    for (int r = 0; r < 4; ++r) {
      bf16x8 av = *(const bf16x8*)(a + (size_t)(r0 + r) * DMODEL + i);
      sum[r] += bf2f(av[0]) * w0.x + bf2f(av[1]) * w0.y + bf2f(av[2]) * w0.z + bf2f(av[3]) * w0.w
              + bf2f(av[4]) * w1.x + bf2f(av[5]) * w1.y + bf2f(av[6]) * w1.z + bf2f(av[7]) * w1.w;
    }
  }
  #pragma unroll
  for (int m = 1; m < 32; m <<= 1) {
    #pragma unroll
    for (int r = 0; r < 4; ++r) sum[r] += __shfl_xor(sum[r], m);
  }
  if (lt == 0) {
    #pragma unroll
    for (int r = 0; r < 4; ++r)
      gs[(size_t)(r0 + r) * 8 + j] = 1.0f / (1.0f + __expf(-(sum[r] + gb[j])));
  }
}

// ------------- key bias = log(sigmoid(hidden @ w2^T + b2) + 0.1) ----------
__global__ __launch_bounds__(256) void imp_kernel(const bf16_t* __restrict__ hid,
                                                  const float* __restrict__ w2,
                                                  const float* __restrict__ b2,
                                                  float* __restrict__ kb) {
  int row = blockIdx.x * 4 + (threadIdx.x >> 6);
  int lane = threadIdx.x & 63;
  const bf16_t* hr = hid + (size_t)row * 512;
  bf16x8 hv = *(const bf16x8*)(hr + lane * 8);
  float sum = 0.0f;
  #pragma unroll
  for (int i = 0; i < 8; ++i) sum += bf2f(hv[i]) * w2[lane * 8 + i];
  #pragma unroll
  for (int m = 1; m < 64; m <<= 1) sum += __shfl_xor(sum, m);
  if (lane == 0) {
    float imp = 1.0f / (1.0f + __expf(-(sum + b2[0])));
    kb[row] = logf(imp + 0.1f);
  }
}

// ---------------- attention: 1 block per (image, head) --------------------
// exp-only softmax (bounded scores) + ones-MFMA row-sum; K/V staged to LDS.
__global__ __launch_bounds__(512, 1) void attn_kernel(
    const bf16_t* __restrict__ Q, const bf16_t* __restrict__ K,
    const bf16_t* __restrict__ V, const float* __restrict__ gs,
    const float* __restrict__ kb, bf16_t* __restrict__ O) {
  __shared__ bf16_t Kt[64 * 128];       // [key][d] swizzled
  __shared__ bf16_t Vt[128 * 64];       // [d][key] swizzled
  __shared__ bf16_t Pl[8][32 * 72];     // per-wave P scratch
  __shared__ float kyf[256], kxf[256], kbl[256];

  const int bi = blockIdx.x >> 4;
  const int h = blockIdx.x & 15;
  const int tid = threadIdx.x;
  const int wid = tid >> 6;
  const int lane = tid & 63;
  const int l15 = lane & 15, l4 = lane >> 4;
  const bool hs = (h < 8);

  for (int i = tid; i < 256; i += 512) {
    kyf[i] = (float)(i / 18);
    kxf[i] = (float)(i % 18);
    int kk = i < SEQ ? i : SEQ - 1;
    kbl[i] = kb[bi * SEQ + kk];
  }

  const int q0 = wid * 32;
  bf16x8 qf[2][4];
  #pragma unroll
  for (int mi = 0; mi < 2; ++mi) {
    int q = q0 + mi * 16 + l15; if (q >= SEQ) q = SEQ - 1;
    const bf16_t* qp = Q + (size_t)(bi * SEQ + q) * DMODEL + h * HDIM;
    #pragma unroll
    for (int ki = 0; ki < 4; ++ki) qf[mi][ki] = *(const bf16x8*)(qp + ki * 32 + l4 * 8);
  }

  const float invdiag = 1.0f / (sqrtf(520.0f) + 1e-6f);
  float gsd[2][4], qyv[2][4], qxv[2][4];
  #pragma unroll
  for (int mi = 0; mi < 2; ++mi)
    #pragma unroll
    for (int j = 0; j < 4; ++j) {
      int q = q0 + mi * 16 + 4 * l4 + j;
      int qc = q < SEQ ? q : SEQ - 1;
      gsd[mi][j] = hs ? gs[(size_t)(bi * SEQ + qc) * 8 + h] * invdiag : 0.0f;
      qyv[mi][j] = (float)(q / 18);
      qxv[mi][j] = (float)(q % 18);
    }

  f32x4v oacc[2][8] = {};
  f32x4v osum[2] = {};
  const float scl = 0.08838834764831845f;       // 1/sqrt(128)
  bf16_t* Plw = &Pl[wid][0];
  bf16x8 vones;
  #pragma unroll
  for (int i = 0; i < 8; ++i) vones[i] = f2bf(1.0f);

  for (int t = 0; t < 4; ++t) {
    __syncthreads();
    #pragma unroll
    for (int rep = 0; rep < 2; ++rep) {
      int s = tid + rep * 512;
      int row = s >> 4, cb = s & 15;
      int kk = t * 64 + row;
      uint4 val = make_uint4(0, 0, 0, 0);
      if (kk < SEQ) val = *(const uint4*)(K + (size_t)(bi * SEQ + kk) * DMODEL + h * HDIM + cb * 8);
      *(uint4*)((char*)Kt + row * 256 + ((cb * 16) ^ ((row & 7) << 4))) = val;
    }
    {
      int kp = tid >> 4, db = tid & 15;
      int k0i = t * 64 + kp * 2, k1i = k0i + 1;
      uint4 a = make_uint4(0, 0, 0, 0), c4 = make_uint4(0, 0, 0, 0);
      if (k0i < SEQ) a = *(const uint4*)(V + (size_t)(bi * SEQ + k0i) * DMODEL + h * HDIM + db * 8);
      if (k1i < SEQ) c4 = *(const uint4*)(V + (size_t)(bi * SEQ + k1i) * DMODEL + h * HDIM + db * 8);
      const ushort_t* au = (const ushort_t*)&a;
      const ushort_t* cu = (const ushort_t*)&c4;
      #pragma unroll
      for (int i = 0; i < 8; ++i) {
        int d = db * 8 + i;
        unsigned pv = (unsigned)au[i] | ((unsigned)cu[i] << 16);
        *(unsigned*)((char*)Vt + d * 128 + ((kp * 4) ^ ((d & 7) << 4))) = pv;
      }
    }
    __syncthreads();

    f32x4v sc[2][4] = {};
    #pragma unroll
    for (int ki = 0; ki < 4; ++ki) {
      bf16x8 kf[4];
      #pragma unroll
      for (int ni = 0; ni < 4; ++ni) {
        int row = ni * 16 + l15;
        kf[ni] = *(const bf16x8*)((char*)Kt + row * 256 + ((ki * 64 + l4 * 16) ^ ((row & 7) << 4)));
      }
      #pragma unroll
      for (int mi = 0; mi < 2; ++mi)
        #pragma unroll
        for (int ni = 0; ni < 4; ++ni)
          sc[mi][ni] = __builtin_amdgcn_mfma_f32_16x16x32_bf16(qf[mi][ki], kf[ni], sc[mi][ni], 0, 0, 0);
    }

    #pragma unroll
    for (int mi = 0; mi < 2; ++mi) {
      #pragma unroll
      for (int j = 0; j < 4; ++j) {
        int prow = mi * 16 + 4 * l4 + j;
        #pragma unroll
        for (int ni = 0; ni < 4; ++ni) {
          int kk = t * 64 + ni * 16 + l15;
          float s = sc[mi][ni][j] * scl + kbl[kk];
          if (hs) {
            float dy = qyv[mi][j] - kyf[kk];
            float dx = qxv[mi][j] - kxf[kk];
            s -= sqrtf(dy * dy + dx * dx) * gsd[mi][j];
          }
          float p = (kk < SEQ) ? __expf(s) : 0.0f;
          Plw[prow * 72 + ni * 16 + l15] = f2bf(p);
        }
      }
    }

    #pragma unroll
    for (int ks = 0; ks < 2; ++ks) {
      bf16x8 pf[2];
      #pragma unroll
      for (int mi = 0; mi < 2; ++mi)
        pf[mi] = *(const bf16x8*)(Plw + (mi * 16 + l15) * 72 + ks * 32 + l4 * 8);
      #pragma unroll
      for (int mi = 0; mi < 2; ++mi)
        osum[mi] = __builtin_amdgcn_mfma_f32_16x16x32_bf16(pf[mi], vones, osum[mi], 0, 0, 0);
      #pragma unroll
      for (int di = 0; di < 8; ++di) {
        int d = di * 16 + l15;
        bf16x8 vf = *(const bf16x8*)((char*)Vt + d * 128 + ((ks * 64 + l4 * 16) ^ ((d & 7) << 4)));
        #pragma unroll
        for (int mi = 0; mi < 2; ++mi)
          oacc[mi][di] = __builtin_amdgcn_mfma_f32_16x16x32_bf16(pf[mi], vf, oacc[mi][di], 0, 0, 0);
      }
    }
  }

  #pragma unroll
  for (int mi = 0; mi < 2; ++mi) {
    #pragma unroll
    for (int j = 0; j < 4; ++j) {
      int q = q0 + mi * 16 + 4 * l4 + j;
      if (q >= SEQ) continue;
      float inv = 1.0f / osum[mi][j];
      bf16_t* op = O + (size_t)(bi * SEQ + q) * DMODEL + h * HDIM;
      #pragma unroll
      for (int di = 0; di < 8; ++di)
        op[di * 16 + l15] = f2bf(oacc[mi][di][j] * inv);
    }
  }
}

// --------------------------------------------------------------------------
extern "C" void kernel_launch(void* const* d_in, const int* in_sizes, int n_in,
                              void* d_out, int out_size, void* d_ws, size_t ws_size,
                              hipStream_t stream) {
  const float* sem  = (const float*)d_in[0];
  const float* vgg  = (const float*)d_in[1];
  const float* ln1w = (const float*)d_in[3];
  const float* ln1b = (const float*)d_in[4];
  const float* ln2w = (const float*)d_in[5];
  const float* ln2b = (const float*)d_in[6];
  const float* Wq   = (const float*)d_in[7];
  const float* Wk   = (const float*)d_in[8];
  const float* Wv   = (const float*)d_in[9];
  const float* Wo   = (const float*)d_in[10];
  const float* w1   = (const float*)d_in[11];
  const float* b1   = (const float*)d_in[12];
  const float* w2   = (const float*)d_in[13];
  const float* b2   = (const float*)d_in[14];
  const float* gw   = (const float*)d_in[15];
  const float* gb   = (const float*)d_in[16];
  const float* gate = (const float*)d_in[17];

  char* ws = (char*)d_ws;
  const size_t SZ_W    = 8388608;    // 2048*2048*2
  const size_t SZ_PAD  = 33554432;   // 8192*2048*2 (padded activations, A-side)
  const size_t SZ_ACT  = 33030144;   // 8064*2048*2
  bf16_t* Wqb  = (bf16_t*)(ws + 0);
  bf16_t* Wkb  = (bf16_t*)(ws + SZ_W);       // Wk;Wv contiguous = fused KV weight
  bf16_t* Wvb  = (bf16_t*)(ws + 2 * SZ_W);
  bf16_t* Wob  = (bf16_t*)(ws + 3 * SZ_W);
  bf16_t* w1b  = (bf16_t*)(ws + 4 * SZ_W);                     // 2 MB
  bf16_t* semb = (bf16_t*)(ws + 4 * SZ_W + 2097152);           // padded; attn-out alias
  bf16_t* vggb = (bf16_t*)(ws + 4 * SZ_W + 2097152 + SZ_PAD);  // padded
  bf16_t* Vb   = (bf16_t*)(ws + 4 * SZ_W + 2097152 + 2 * SZ_PAD);
  bf16_t* hidb = (bf16_t*)(ws + 4 * SZ_W + 2097152 + 2 * SZ_PAD + SZ_ACT);
  float*  gsb  = (float*)(ws + 4 * SZ_W + 2097152 + 2 * SZ_PAD + SZ_ACT + 8257536);
  float*  kbb  = (float*)(ws + 4 * SZ_W + 2097152 + 2 * SZ_PAD + SZ_ACT + 8257536 + 258048);
  // Q and K (8064 rows each, bf16) exactly fill d_out (8064*2048*4 B)
  bf16_t* Qb = (bf16_t*)d_out;
  bf16_t* Kb = (bf16_t*)((char*)d_out + SZ_ACT);
  bf16_t* attnb = semb;

  cvt4_kernel<<<dim3(2048, 4), 256, 0, stream>>>(Wq, Wk, Wv, Wo, Wqb, Wkb, Wvb, Wob);
  cvt_kernel<<<512, 256, 0, stream>>>(w1, w1b, 1048576);
  ln_kernel<<<dim3(8064, 2), 256, 0, stream>>>(sem, vgg, ln1w, ln1b, ln2w, ln2b, semb, vggb);

  // Q projection: 8192(pad)x2048x2048
  gemm256<0><<<256, 512, 0, stream>>>(semb, Wqb, Qb, nullptr, nullptr,
                                      8064, 2048, 2048, 8);
  // fused K+V projection: 8192(pad)x4096x2048 (Wk;Wv adjacent)
  gemm256<3><<<512, 512, 0, stream>>>(vggb, Wkb, Kb, Vb, nullptr,
                                      8064, 4096, 2048, 16);
  // importance hidden: 8064x512x2048, relu+bias (128^2 kernel)
  gemm_bt<1><<<252, 256, 0, stream>>>(semb, w1b, hidb, nullptr, b1, nullptr,
                                      8064, 512, 2048, 4);

  gate_kernel<<<2016, 256, 0, stream>>>(semb, gw, gb, gsb);
  imp_kernel<<<2016, 256, 0, stream>>>(hidb, w2, b2, kbb);

  attn_kernel<<<512, 512, 0, stream>>>(Qb, Kb, Vb, gsb, kbb, attnb);

  // output projection: 8192(pad)x2048x2048, *tanh(gate), f32 out
  gemm256<2><<<256, 512, 0, stream>>>(attnb, Wob, d_out, nullptr, gate,
                                      8064, 2048, 2048, 8);
}